// Round 11
// baseline (341.082 us; speedup 1.0000x reference)
//
#include <hip/hip_runtime.h>
#include <math.h>

// ---------------------------------------------------------------------------
// Encoder: GCN(2 layers) + per-graph mean pool + FF MLP on pooled rows + sigmoid
// N=100000 nodes, E=1600000 edges, D=128, G=256 graphs (graph_id sorted)
// Round 11: SpMM gather loop restructured for real memory-level parallelism.
//   r10 post-mortem: VGPR_Count=20 proves compiler serialized the "unroll 8"
//   gathers (load->wait->use). Now: full 16-edge tiles, two explicit batches
//   of 8 gathers into named registers (static-indexed arrays, full unroll)
//   -> 8 global_load_dwordx4 in flight per wave before first consume.
// ---------------------------------------------------------------------------

#define D 128
#define G 256
#define NB 512     // dst buckets (rows-per-bucket = ceil(N/NB) = 196 <= 256)
#define NBLK 512   // scatter blocks (each owns a contiguous edge chunk)

typedef __attribute__((ext_vector_type(8))) short bf16x8;
typedef __attribute__((ext_vector_type(4))) float f32x4;

__device__ __forceinline__ unsigned short f2bf(float f) {
    unsigned u = __float_as_uint(f);
    unsigned r = (u + 0x7fffu + ((u >> 16) & 1u)) >> 16;   // round-nearest-even
    return (unsigned short)r;
}

// ---- one-time: WT[c][k] = bf16(W[k][c]) for both weight matrices
__global__ __launch_bounds__(256)
void prep_wt2(const float* __restrict__ W1, short* __restrict__ WT1,
              const float* __restrict__ W2, short* __restrict__ WT2) {
    int idx = blockIdx.x * 256 + threadIdx.x;
    int m = idx & 16383;
    int k = m >> 7, c = m & 127;
    if (idx < 16384)
        WT1[c * 128 + k] = (short)f2bf(W1[k * 128 + c]);
    else
        WT2[c * 128 + k] = (short)f2bf(W2[k * 128 + c]);
}

// ---- MFMA GEMM (fp32 input): Y_bf16 = X_f32 @ W   (WT = W^T bf16)
__global__ __launch_bounds__(256, 2)
void gemm_mfma_f32in(const float* __restrict__ X, const short* __restrict__ WT,
                     short* __restrict__ Y, int nrows) {
    const int lane = threadIdx.x & 63;
    const int lr = lane & 15;
    const int lq = lane >> 4;
    const int wid = blockIdx.x * 4 + (threadIdx.x >> 6);
    const int nwaves = gridDim.x * 4;
    const int ngroups = (nrows + 15) >> 4;

    bf16x8 wf[8][4];
#pragma unroll
    for (int mt = 0; mt < 8; mt++)
#pragma unroll
        for (int ks = 0; ks < 4; ks++)
            wf[mt][ks] = *(const bf16x8*)(WT + (mt * 16 + lr) * 128 + ks * 32 + lq * 8);

    for (int g = wid; g < ngroups; g += nwaves) {
        int node = g * 16 + lr;
        int nrow = min(node, nrows - 1);
        const float* xp = X + (size_t)nrow * D + lq * 8;
        f32x4 acc[8];
#pragma unroll
        for (int mt = 0; mt < 8; mt++) acc[mt] = (f32x4){0.f, 0.f, 0.f, 0.f};

#pragma unroll
        for (int ks = 0; ks < 4; ks++) {
            float4 v0 = *(const float4*)(xp + ks * 32);
            float4 v1 = *(const float4*)(xp + ks * 32 + 4);
            bf16x8 xb;
            xb[0] = (short)f2bf(v0.x);
            xb[1] = (short)f2bf(v0.y);
            xb[2] = (short)f2bf(v0.z);
            xb[3] = (short)f2bf(v0.w);
            xb[4] = (short)f2bf(v1.x);
            xb[5] = (short)f2bf(v1.y);
            xb[6] = (short)f2bf(v1.z);
            xb[7] = (short)f2bf(v1.w);
#pragma unroll
            for (int mt = 0; mt < 8; mt++)
                acc[mt] = __builtin_amdgcn_mfma_f32_16x16x32_bf16(wf[mt][ks], xb, acc[mt], 0, 0, 0);
        }

        if (node < nrows) {
            short* yp = Y + (size_t)node * D + lq * 4;
#pragma unroll
            for (int mt = 0; mt < 8; mt++) {
                ushort4 o;
                o.x = f2bf(acc[mt][0]);
                o.y = f2bf(acc[mt][1]);
                o.z = f2bf(acc[mt][2]);
                o.w = f2bf(acc[mt][3]);
                *(ushort4*)(yp + mt * 16) = o;
            }
        }
    }
}

// ---- MFMA GEMM (bf16 input): Y_bf16 = X_bf16 @ W  (direct frag loads, no cvt)
__global__ __launch_bounds__(256, 2)
void gemm_mfma_bf16in(const unsigned short* __restrict__ X, const short* __restrict__ WT,
                      short* __restrict__ Y, int nrows) {
    const int lane = threadIdx.x & 63;
    const int lr = lane & 15;
    const int lq = lane >> 4;
    const int wid = blockIdx.x * 4 + (threadIdx.x >> 6);
    const int nwaves = gridDim.x * 4;
    const int ngroups = (nrows + 15) >> 4;

    bf16x8 wf[8][4];
#pragma unroll
    for (int mt = 0; mt < 8; mt++)
#pragma unroll
        for (int ks = 0; ks < 4; ks++)
            wf[mt][ks] = *(const bf16x8*)(WT + (mt * 16 + lr) * 128 + ks * 32 + lq * 8);

    for (int g = wid; g < ngroups; g += nwaves) {
        int node = g * 16 + lr;
        int nrow = min(node, nrows - 1);
        const unsigned short* xp = X + (size_t)nrow * D + lq * 8;
        f32x4 acc[8];
#pragma unroll
        for (int mt = 0; mt < 8; mt++) acc[mt] = (f32x4){0.f, 0.f, 0.f, 0.f};

#pragma unroll
        for (int ks = 0; ks < 4; ks++) {
            bf16x8 xb = *(const bf16x8*)(xp + ks * 32);
#pragma unroll
            for (int mt = 0; mt < 8; mt++)
                acc[mt] = __builtin_amdgcn_mfma_f32_16x16x32_bf16(wf[mt][ks], xb, acc[mt], 0, 0, 0);
        }

        if (node < nrows) {
            short* yp = Y + (size_t)node * D + lq * 4;
#pragma unroll
            for (int mt = 0; mt < 8; mt++) {
                ushort4 o;
                o.x = f2bf(acc[mt][0]);
                o.y = f2bf(acc[mt][1]);
                o.z = f2bf(acc[mt][2]);
                o.w = f2bf(acc[mt][3]);
                *(ushort4*)(yp + mt * 16) = o;
            }
        }
    }
}

// ============== CSR build: atomic-free radix partition + bucket sort ========

__global__ __launch_bounds__(256)
void radix_count(const int* __restrict__ dst, int* __restrict__ counts,
                 int ne, int rpb, int chunk) {
    __shared__ int h[NB];
    for (int i = threadIdx.x; i < NB; i += 256) h[i] = 0;
    __syncthreads();
    int b = blockIdx.x;
    int lo = b * chunk, hi = min(lo + chunk, ne);
    for (int e = lo + threadIdx.x; e < hi; e += 256)
        atomicAdd(&h[dst[e] / rpb], 1);
    __syncthreads();
    for (int k = threadIdx.x; k < NB; k += 256)
        counts[k * NBLK + b] = h[k];
}

__global__ __launch_bounds__(256)
void radix_scan_rel(int* __restrict__ counts, int* __restrict__ bsum) {
    __shared__ int s[256];
    int k = blockIdx.x, t = threadIdx.x;
    int base = k * NBLK + t * 2;
    int v0 = counts[base], v1 = counts[base + 1];
    int sum = v0 + v1;
    s[t] = sum;
    __syncthreads();
    for (int off = 1; off < 256; off <<= 1) {
        int x = (t >= off) ? s[t - off] : 0;
        __syncthreads();
        s[t] += x;
        __syncthreads();
    }
    int ex = s[t] - sum;
    counts[base] = ex;
    counts[base + 1] = ex + v0;
    if (t == 255) bsum[k] = s[255];
}

__global__ __launch_bounds__(NB)
void radix_base(const int* __restrict__ bsum, int* __restrict__ bbase,
                int* __restrict__ row_ptr, int ne, int n) {
    __shared__ int s[NB];
    int t = threadIdx.x;
    int v = bsum[t];
    s[t] = v;
    __syncthreads();
    for (int off = 1; off < NB; off <<= 1) {
        int x = (t >= off) ? s[t - off] : 0;
        __syncthreads();
        s[t] += x;
        __syncthreads();
    }
    bbase[t + 1] = s[t];
    if (t == 0) { bbase[0] = 0; row_ptr[n] = ne; }
}

__global__ __launch_bounds__(256)
void radix_scatter(const int* __restrict__ src, const int* __restrict__ dst,
                   const float* __restrict__ ew,
                   const int* __restrict__ counts, const int* __restrict__ bbase,
                   int2* __restrict__ tmp_sw, unsigned short* __restrict__ tmp_lr,
                   int ne, int rpb, int chunk) {
    __shared__ int cur[NB];
    int b = blockIdx.x;
    for (int k = threadIdx.x; k < NB; k += 256)
        cur[k] = bbase[k] + counts[k * NBLK + b];
    __syncthreads();
    int lo = b * chunk, hi = min(lo + chunk, ne);
    for (int e = lo + threadIdx.x; e < hi; e += 256) {
        int d = dst[e];
        int k = d / rpb;
        int pos = atomicAdd(&cur[k], 1);          // LDS atomic
        tmp_sw[pos] = make_int2(src[e], __float_as_int(ew[e]));
        tmp_lr[pos] = (unsigned short)(d - k * rpb);
    }
}

__global__ __launch_bounds__(256)
void bucket_sort(const unsigned short* __restrict__ tmp_lr,
                 const int2* __restrict__ tmp_sw,
                 const int* __restrict__ bbase, int2* __restrict__ ep,
                 int* __restrict__ row_ptr, int n, int rpb) {
    __shared__ int cnt[256], scn[256], cur[256];
    int b = blockIdx.x, t = threadIdx.x;
    int e0 = bbase[b], e1 = bbase[b + 1];
    int r0 = b * rpb;
    cnt[t] = 0;
    __syncthreads();
    for (int i = e0 + t; i < e1; i += 256)
        atomicAdd(&cnt[tmp_lr[i]], 1);
    __syncthreads();
    int v = cnt[t];
    scn[t] = v;
    __syncthreads();
    for (int off = 1; off < 256; off <<= 1) {
        int x = (t >= off) ? scn[t - off] : 0;
        __syncthreads();
        scn[t] += x;
        __syncthreads();
    }
    int ex = scn[t] - v;
    cur[t] = ex;
    int grow = r0 + t;
    if (t < rpb && grow < n) row_ptr[grow] = e0 + ex;
    __syncthreads();
    for (int i = e0 + t; i < e1; i += 256) {
        int r = tmp_lr[i];
        int pos = e0 + atomicAdd(&cur[r], 1);     // LDS atomic
        ep[pos] = tmp_sw[i];
    }
}

// ---- Gather SpMM: quarter-wave (16 lanes x uint4 = 256B) per row.
// Full 16-edge tiles: 2 batches of 8 explicitly named in-flight gathers.
// FUSE=true: out = bf16(relu(acc + bias)) packed; else out = fp32 acc.
template<bool FUSE>
__global__ __launch_bounds__(256)
void spmm_csr(const uint4* __restrict__ Xu4, const long long* __restrict__ ep,
              const int* __restrict__ rp, const float* __restrict__ bias,
              void* __restrict__ outv, int nrows) {
    int row = blockIdx.x * 16 + (threadIdx.x >> 4);
    if (row >= nrows) return;
    int l = threadIdx.x & 15;             // dim-octet index (8 dims)
    int beg = rp[row], end = rp[row + 1];
    float a0 = 0.f, a1 = 0.f, a2 = 0.f, a3 = 0.f,
          a4 = 0.f, a5 = 0.f, a6 = 0.f, a7 = 0.f;

    int j = beg;
    // ---- full 16-edge tiles: batched gathers (8 in flight) ----
    for (; j + 16 <= end; j += 16) {
        long long epk = __builtin_nontemporal_load(ep + j + l);
#pragma unroll
        for (int half = 0; half < 2; half++) {
            uint4 u[8];
            float w[8];
#pragma unroll
            for (int t = 0; t < 8; t++) {
                long long eb = __shfl(epk, half * 8 + t, 16);
                w[t] = __uint_as_float((unsigned)((unsigned long long)eb >> 32));
                u[t] = Xu4[(size_t)(int)(eb & 0xffffffffll) * 16 + l];
            }
#pragma unroll
            for (int t = 0; t < 8; t++) {
                a0 = fmaf(w[t], __uint_as_float(u[t].x << 16), a0);
                a1 = fmaf(w[t], __uint_as_float(u[t].x & 0xffff0000u), a1);
                a2 = fmaf(w[t], __uint_as_float(u[t].y << 16), a2);
                a3 = fmaf(w[t], __uint_as_float(u[t].y & 0xffff0000u), a3);
                a4 = fmaf(w[t], __uint_as_float(u[t].z << 16), a4);
                a5 = fmaf(w[t], __uint_as_float(u[t].z & 0xffff0000u), a5);
                a6 = fmaf(w[t], __uint_as_float(u[t].w << 16), a6);
                a7 = fmaf(w[t], __uint_as_float(u[t].w & 0xffff0000u), a7);
            }
        }
    }
    // ---- remainder (<16 edges): uniform-address metadata loads ----
    for (; j < end; j++) {
        long long eb = ep[j];
        float w = __uint_as_float((unsigned)((unsigned long long)eb >> 32));
        uint4 u = Xu4[(size_t)(int)(eb & 0xffffffffll) * 16 + l];
        a0 = fmaf(w, __uint_as_float(u.x << 16), a0);
        a1 = fmaf(w, __uint_as_float(u.x & 0xffff0000u), a1);
        a2 = fmaf(w, __uint_as_float(u.y << 16), a2);
        a3 = fmaf(w, __uint_as_float(u.y & 0xffff0000u), a3);
        a4 = fmaf(w, __uint_as_float(u.z << 16), a4);
        a5 = fmaf(w, __uint_as_float(u.z & 0xffff0000u), a5);
        a6 = fmaf(w, __uint_as_float(u.w << 16), a6);
        a7 = fmaf(w, __uint_as_float(u.w & 0xffff0000u), a7);
    }

    if (FUSE) {
        // relu(acc + b1) -> packed bf16 (layer-1 epilogue fused)
        const float4 b0 = *(const float4*)(bias + l * 8);
        const float4 b1v = *(const float4*)(bias + l * 8 + 4);
        a0 = fmaxf(a0 + b0.x, 0.f);  a1 = fmaxf(a1 + b0.y, 0.f);
        a2 = fmaxf(a2 + b0.z, 0.f);  a3 = fmaxf(a3 + b0.w, 0.f);
        a4 = fmaxf(a4 + b1v.x, 0.f); a5 = fmaxf(a5 + b1v.y, 0.f);
        a6 = fmaxf(a6 + b1v.z, 0.f); a7 = fmaxf(a7 + b1v.w, 0.f);
        uint4 p;
        p.x = (unsigned)f2bf(a0) | ((unsigned)f2bf(a1) << 16);
        p.y = (unsigned)f2bf(a2) | ((unsigned)f2bf(a3) << 16);
        p.z = (unsigned)f2bf(a4) | ((unsigned)f2bf(a5) << 16);
        p.w = (unsigned)f2bf(a6) | ((unsigned)f2bf(a7) << 16);
        *((uint4*)outv + (size_t)row * 16 + l) = p;   // bf16 row = 16 uint4
    } else {
        float* op = (float*)outv + (size_t)row * D + l * 8;
        *(f32x4*)op = (f32x4){a0, a1, a2, a3};
        *(f32x4*)(op + 4) = (f32x4){a4, a5, a6, a7};
    }
}

// ======================= graph pooling + FF =================================

__global__ __launch_bounds__(256)
void bounds_kernel(const int* __restrict__ gid, int* __restrict__ ptr, int n) {
    int i = blockIdx.x * 256 + threadIdx.x;
    if (i >= n) return;
    int b = gid[i];
    int a = (i == 0) ? -1 : gid[i - 1];
    for (int g = a + 1; g <= b; g++) ptr[g] = i;
    if (i == n - 1) {
        for (int g = b + 1; g <= G; g++) ptr[g] = n;
    }
}

__global__ __launch_bounds__(512)
void pool_kernel(const float* __restrict__ S, const int* __restrict__ ptr,
                 const float* __restrict__ b2, float* __restrict__ pooled) {
    __shared__ float red[4][128];
    int g = blockIdx.x;
    int d = threadIdx.x & 127;
    int r = threadIdx.x >> 7;
    int beg = ptr[g], end = ptr[g + 1];
    float acc = 0.f;
    for (int n = beg + r; n < end; n += 4) acc += S[(size_t)n * D + d];
    red[r][d] = acc;
    __syncthreads();
    if (r == 0) {
        float s = red[0][d] + red[1][d] + red[2][d] + red[3][d];
        int cnt = end - beg;
        pooled[g * D + d] = (cnt > 0) ? (s / (float)cnt + b2[d]) : 0.f;
    }
}

__global__ __launch_bounds__(128)
void ff_kernel(const float* __restrict__ pooled,
               const float* __restrict__ W1, const float* __restrict__ b1,
               const float* __restrict__ W2, const float* __restrict__ b2,
               const float* __restrict__ W3, const float* __restrict__ b3,
               const float* __restrict__ Wsc, const float* __restrict__ bsc,
               float* __restrict__ ffout) {
    __shared__ float hx[D], za[D], zb[D];
    int g = blockIdx.x, d = threadIdx.x;
    hx[d] = pooled[g * D + d];
    __syncthreads();
    float s = b1[d];
    for (int k = 0; k < D; k++) s = fmaf(hx[k], W1[k * D + d], s);
    za[d] = fmaxf(s, 0.f);
    __syncthreads();
    s = b2[d];
    for (int k = 0; k < D; k++) s = fmaf(za[k], W2[k * D + d], s);
    zb[d] = fmaxf(s, 0.f);
    __syncthreads();
    s = b3[d];
    for (int k = 0; k < D; k++) s = fmaf(zb[k], W3[k * D + d], s);
    float z3 = fmaxf(s, 0.f);
    float sc = bsc[d];
    for (int k = 0; k < D; k++) sc = fmaf(hx[k], Wsc[k * D + d], sc);
    float v = z3 + sc;
    ffout[g * D + d] = 1.f / (1.f + expf(-v));
}

__global__ __launch_bounds__(256)
void scatter_kernel(const float* __restrict__ ffout, const int* __restrict__ gid,
                    float* __restrict__ out, int n) {
    unsigned idx = blockIdx.x * 256u + threadIdx.x;
    unsigned node = idx >> 5;
    if (node >= (unsigned)n) return;
    int d0 = (idx & 31) * 4;
    int g = gid[node];
    *(float4*)(out + (size_t)node * D + d0) = *(const float4*)(ffout + g * D + d0);
}

extern "C" void kernel_launch(void* const* d_in, const int* in_sizes, int n_in,
                              void* d_out, int out_size, void* d_ws, size_t ws_size,
                              hipStream_t stream) {
    const float* feat = (const float*)d_in[0];
    const float* ew   = (const float*)d_in[1];
    const float* W1   = (const float*)d_in[2];
    const float* b1   = (const float*)d_in[3];
    const float* W2   = (const float*)d_in[4];
    const float* b2   = (const float*)d_in[5];
    const float* ffW1 = (const float*)d_in[6];
    const float* ffb1 = (const float*)d_in[7];
    const float* ffW2 = (const float*)d_in[8];
    const float* ffb2 = (const float*)d_in[9];
    const float* ffW3 = (const float*)d_in[10];
    const float* ffb3 = (const float*)d_in[11];
    const float* ffWs = (const float*)d_in[12];
    const float* ffbs = (const float*)d_in[13];
    const int* esrc = (const int*)d_in[14];
    const int* edst = (const int*)d_in[15];
    const int* gid  = (const int*)d_in[16];

    const int N = in_sizes[0] / D;
    const int E = in_sizes[1];
    float* out = (float*)d_out;

    const int rpb = (N + NB - 1) / NB;        // 196 (<=256 required by bucket_sort)
    const int chunk = (E + NBLK - 1) / NBLK;  // edges per scatter block

    // workspace layout
    char* ws = (char*)d_ws;
    int2* ep = (int2*)ws;                                   // E int2 = 12.8MB
    unsigned short* A = (unsigned short*)(ep + E);          // N*128 bf16 = 25.6MB
    // build temporaries alias A (A written only after build completes)
    int2* tmp_sw = (int2*)A;                                // E int2 = 12.8MB
    unsigned short* tmp_lr = (unsigned short*)(tmp_sw + E); // E u16  =  3.2MB
    float* pooled = (float*)(A + (size_t)N * D);            // G*D
    float* ffo = pooled + G * D;                            // G*D
    int* gptr = (int*)(ffo + G * D);                        // G+1
    int* row_ptr = gptr + G + 2;                            // N+1
    int* bbase = row_ptr + N + 1;                           // NB+1
    int* bsum = bbase + NB + 1;                             // NB
    int* counts = bsum + NB;                                // NB*NBLK = 1MB
    short* WT1 = (short*)(counts + NB * NBLK);              // 128*128 bf16
    short* WT2 = WT1 + 128 * 128;                           // 128*128 bf16

    unsigned short* S1 = (unsigned short*)d_out;  // bf16 layer-1 act (front 25.6MB of out)
    float* S2 = out;                              // fp32 layer-2 spmm result (full out)

    const dim3 blk(256);
    const int nGrid = (N + 255) / 256;
    const int ngroups = (N + 15) / 16;
    const int gemmGrid = (ngroups + 7) / 8;   // ~2 groups per wave

    // ---- weight transpose+bf16 (tiny, once per call)
    prep_wt2<<<128, blk, 0, stream>>>(W1, WT1, W2, WT2);

    // ---- CSR build (atomic-free radix partition; LDS atomics only)
    radix_count<<<NBLK, blk, 0, stream>>>(edst, counts, E, rpb, chunk);
    radix_scan_rel<<<NB, blk, 0, stream>>>(counts, bsum);
    radix_base<<<1, NB, 0, stream>>>(bsum, bbase, row_ptr, E, N);
    radix_scatter<<<NBLK, blk, 0, stream>>>(esrc, edst, ew, counts, bbase,
                                            tmp_sw, tmp_lr, E, rpb, chunk);
    bucket_sort<<<NB, blk, 0, stream>>>(tmp_lr, tmp_sw, bbase, ep, row_ptr, N, rpb);

    // ---- graph boundaries from sorted gid
    bounds_kernel<<<nGrid, blk, 0, stream>>>(gid, gptr, N);

    // ---- pipeline
    // A1 = feat @ W1 (bf16)
    gemm_mfma_f32in<<<gemmGrid, blk, 0, stream>>>(feat, WT1, (short*)A, N);
    // S1 = bf16(relu(spmm(A1) + b1))   [fused epilogue]
    spmm_csr<true><<<(N + 15) / 16, blk, 0, stream>>>((const uint4*)A, (const long long*)ep,
                                                      row_ptr, b1, S1, N);
    // A2 = S1 @ W2 (pure bf16 GEMM)
    gemm_mfma_bf16in<<<gemmGrid, blk, 0, stream>>>(S1, WT2, (short*)A, N);
    // S2 = spmm(A2) fp32  (b2 added in pool)
    spmm_csr<false><<<(N + 15) / 16, blk, 0, stream>>>((const uint4*)A, (const long long*)ep,
                                                       row_ptr, nullptr, S2, N);

    // ---- per-graph mean pool + FF + scatter
    pool_kernel<<<G, 512, 0, stream>>>(S2, gptr, b2, pooled);
    ff_kernel<<<G, 128, 0, stream>>>(pooled, ffW1, ffb1, ffW2, ffb2,
                                     ffW3, ffb3, ffWs, ffbs, ffo);
    scatter_kernel<<<(int)(((size_t)N * 32 + 255) / 256), blk, 0, stream>>>(ffo, gid, out, N);
}

// Round 12
// 259.854 us; speedup vs baseline: 1.3126x; 1.3126x over previous
//
#include <hip/hip_runtime.h>
#include <math.h>

// ---------------------------------------------------------------------------
// Encoder: GCN(2 layers) + per-graph mean pool + FF MLP on pooled rows + sigmoid
// N=100000 nodes, E=1600000 edges, D=128, G=256 graphs (graph_id sorted)
// Round 12:
//  - REVERT r11 gather batching (VGPR 20->36 but 68->80us: gather-service
//    bound, not MLP bound). Back to r10 loop form.
//  - ALGEBRAIC: layer-2 output feeds ONLY the linear mean-pool =>
//    pooled[g] = (Sum_{e:dst in g} w_e * S1[src_e]) @ W2 / cnt + b2.
//    New graph_sum kernel does the edge gather-sum into 256x128 (edges are
//    graph-contiguous in CSR because nodes are sorted by graph); W2 applied
//    to the tiny pooled matrix inside ff_kernel. Deletes gemm2 (~20us),
//    spmm2's 50MB write (~8us), pool_kernel's 51MB read (~12us).
// ---------------------------------------------------------------------------

#define D 128
#define G 256
#define NB 512     // dst buckets (rows-per-bucket = ceil(N/NB) = 196 <= 256)
#define NBLK 512   // scatter blocks (each owns a contiguous edge chunk)
#define SPLIT 8    // partial-sum blocks per graph in graph_sum (deterministic)

typedef __attribute__((ext_vector_type(8))) short bf16x8;
typedef __attribute__((ext_vector_type(4))) float f32x4;

__device__ __forceinline__ unsigned short f2bf(float f) {
    unsigned u = __float_as_uint(f);
    unsigned r = (u + 0x7fffu + ((u >> 16) & 1u)) >> 16;   // round-nearest-even
    return (unsigned short)r;
}

// ---- one-time: WT1[c][k] = bf16(W1[k][c])  (128x128)
__global__ __launch_bounds__(256)
void prep_wt(const float* __restrict__ W, short* __restrict__ WT) {
    int idx = blockIdx.x * 256 + threadIdx.x;
    if (idx >= 128 * 128) return;
    int k = idx >> 7, c = idx & 127;
    WT[c * 128 + k] = (short)f2bf(W[k * 128 + c]);
}

// ---- MFMA GEMM (fp32 input): Y_bf16 = X_f32 @ W   (WT = W^T bf16)
__global__ __launch_bounds__(256, 2)
void gemm_mfma_f32in(const float* __restrict__ X, const short* __restrict__ WT,
                     short* __restrict__ Y, int nrows) {
    const int lane = threadIdx.x & 63;
    const int lr = lane & 15;
    const int lq = lane >> 4;
    const int wid = blockIdx.x * 4 + (threadIdx.x >> 6);
    const int nwaves = gridDim.x * 4;
    const int ngroups = (nrows + 15) >> 4;

    bf16x8 wf[8][4];
#pragma unroll
    for (int mt = 0; mt < 8; mt++)
#pragma unroll
        for (int ks = 0; ks < 4; ks++)
            wf[mt][ks] = *(const bf16x8*)(WT + (mt * 16 + lr) * 128 + ks * 32 + lq * 8);

    for (int g = wid; g < ngroups; g += nwaves) {
        int node = g * 16 + lr;
        int nrow = min(node, nrows - 1);
        const float* xp = X + (size_t)nrow * D + lq * 8;
        f32x4 acc[8];
#pragma unroll
        for (int mt = 0; mt < 8; mt++) acc[mt] = (f32x4){0.f, 0.f, 0.f, 0.f};

#pragma unroll
        for (int ks = 0; ks < 4; ks++) {
            float4 v0 = *(const float4*)(xp + ks * 32);
            float4 v1 = *(const float4*)(xp + ks * 32 + 4);
            bf16x8 xb;
            xb[0] = (short)f2bf(v0.x);
            xb[1] = (short)f2bf(v0.y);
            xb[2] = (short)f2bf(v0.z);
            xb[3] = (short)f2bf(v0.w);
            xb[4] = (short)f2bf(v1.x);
            xb[5] = (short)f2bf(v1.y);
            xb[6] = (short)f2bf(v1.z);
            xb[7] = (short)f2bf(v1.w);
#pragma unroll
            for (int mt = 0; mt < 8; mt++)
                acc[mt] = __builtin_amdgcn_mfma_f32_16x16x32_bf16(wf[mt][ks], xb, acc[mt], 0, 0, 0);
        }

        if (node < nrows) {
            short* yp = Y + (size_t)node * D + lq * 4;
#pragma unroll
            for (int mt = 0; mt < 8; mt++) {
                ushort4 o;
                o.x = f2bf(acc[mt][0]);
                o.y = f2bf(acc[mt][1]);
                o.z = f2bf(acc[mt][2]);
                o.w = f2bf(acc[mt][3]);
                *(ushort4*)(yp + mt * 16) = o;
            }
        }
    }
}

// ============== CSR build: atomic-free radix partition + bucket sort ========

__global__ __launch_bounds__(256)
void radix_count(const int* __restrict__ dst, int* __restrict__ counts,
                 int ne, int rpb, int chunk) {
    __shared__ int h[NB];
    for (int i = threadIdx.x; i < NB; i += 256) h[i] = 0;
    __syncthreads();
    int b = blockIdx.x;
    int lo = b * chunk, hi = min(lo + chunk, ne);
    for (int e = lo + threadIdx.x; e < hi; e += 256)
        atomicAdd(&h[dst[e] / rpb], 1);
    __syncthreads();
    for (int k = threadIdx.x; k < NB; k += 256)
        counts[k * NBLK + b] = h[k];
}

__global__ __launch_bounds__(256)
void radix_scan_rel(int* __restrict__ counts, int* __restrict__ bsum) {
    __shared__ int s[256];
    int k = blockIdx.x, t = threadIdx.x;
    int base = k * NBLK + t * 2;
    int v0 = counts[base], v1 = counts[base + 1];
    int sum = v0 + v1;
    s[t] = sum;
    __syncthreads();
    for (int off = 1; off < 256; off <<= 1) {
        int x = (t >= off) ? s[t - off] : 0;
        __syncthreads();
        s[t] += x;
        __syncthreads();
    }
    int ex = s[t] - sum;
    counts[base] = ex;
    counts[base + 1] = ex + v0;
    if (t == 255) bsum[k] = s[255];
}

__global__ __launch_bounds__(NB)
void radix_base(const int* __restrict__ bsum, int* __restrict__ bbase,
                int* __restrict__ row_ptr, int ne, int n) {
    __shared__ int s[NB];
    int t = threadIdx.x;
    int v = bsum[t];
    s[t] = v;
    __syncthreads();
    for (int off = 1; off < NB; off <<= 1) {
        int x = (t >= off) ? s[t - off] : 0;
        __syncthreads();
        s[t] += x;
        __syncthreads();
    }
    bbase[t + 1] = s[t];
    if (t == 0) { bbase[0] = 0; row_ptr[n] = ne; }
}

__global__ __launch_bounds__(256)
void radix_scatter(const int* __restrict__ src, const int* __restrict__ dst,
                   const float* __restrict__ ew,
                   const int* __restrict__ counts, const int* __restrict__ bbase,
                   int2* __restrict__ tmp_sw, unsigned short* __restrict__ tmp_lr,
                   int ne, int rpb, int chunk) {
    __shared__ int cur[NB];
    int b = blockIdx.x;
    for (int k = threadIdx.x; k < NB; k += 256)
        cur[k] = bbase[k] + counts[k * NBLK + b];
    __syncthreads();
    int lo = b * chunk, hi = min(lo + chunk, ne);
    for (int e = lo + threadIdx.x; e < hi; e += 256) {
        int d = dst[e];
        int k = d / rpb;
        int pos = atomicAdd(&cur[k], 1);          // LDS atomic
        tmp_sw[pos] = make_int2(src[e], __float_as_int(ew[e]));
        tmp_lr[pos] = (unsigned short)(d - k * rpb);
    }
}

__global__ __launch_bounds__(256)
void bucket_sort(const unsigned short* __restrict__ tmp_lr,
                 const int2* __restrict__ tmp_sw,
                 const int* __restrict__ bbase, int2* __restrict__ ep,
                 int* __restrict__ row_ptr, int n, int rpb) {
    __shared__ int cnt[256], scn[256], cur[256];
    int b = blockIdx.x, t = threadIdx.x;
    int e0 = bbase[b], e1 = bbase[b + 1];
    int r0 = b * rpb;
    cnt[t] = 0;
    __syncthreads();
    for (int i = e0 + t; i < e1; i += 256)
        atomicAdd(&cnt[tmp_lr[i]], 1);
    __syncthreads();
    int v = cnt[t];
    scn[t] = v;
    __syncthreads();
    for (int off = 1; off < 256; off <<= 1) {
        int x = (t >= off) ? scn[t - off] : 0;
        __syncthreads();
        scn[t] += x;
        __syncthreads();
    }
    int ex = scn[t] - v;
    cur[t] = ex;
    int grow = r0 + t;
    if (t < rpb && grow < n) row_ptr[grow] = e0 + ex;
    __syncthreads();
    for (int i = e0 + t; i < e1; i += 256) {
        int r = tmp_lr[i];
        int pos = e0 + atomicAdd(&cur[r], 1);     // LDS atomic
        ep[pos] = tmp_sw[i];
    }
}

// ---- Layer-1 SpMM (r10 form): quarter-wave per row, fused relu(.+b1)->bf16
__global__ __launch_bounds__(256)
void spmm_csr_fused(const uint4* __restrict__ Xu4, const long long* __restrict__ ep,
                    const int* __restrict__ rp, const float* __restrict__ bias,
                    uint4* __restrict__ outv, int nrows) {
    int row = blockIdx.x * 16 + (threadIdx.x >> 4);
    if (row >= nrows) return;
    int l = threadIdx.x & 15;             // dim-octet index (8 dims)
    int beg = rp[row], end = rp[row + 1];
    float a0 = 0.f, a1 = 0.f, a2 = 0.f, a3 = 0.f,
          a4 = 0.f, a5 = 0.f, a6 = 0.f, a7 = 0.f;

    for (int t0 = beg; t0 < end; t0 += 16) {
        int j = t0 + l;
        long long epk = (j < end) ? __builtin_nontemporal_load(ep + j) : 0ll;
        int cnt = min(16, end - t0);
#pragma unroll 8
        for (int t = 0; t < cnt; t++) {
            long long ebc = __shfl(epk, t, 16);
            int s = (int)(ebc & 0xffffffffll);
            float w = __uint_as_float((unsigned)((unsigned long long)ebc >> 32));
            uint4 u = Xu4[(size_t)s * 16 + l];
            a0 = fmaf(w, __uint_as_float(u.x << 16), a0);
            a1 = fmaf(w, __uint_as_float(u.x & 0xffff0000u), a1);
            a2 = fmaf(w, __uint_as_float(u.y << 16), a2);
            a3 = fmaf(w, __uint_as_float(u.y & 0xffff0000u), a3);
            a4 = fmaf(w, __uint_as_float(u.z << 16), a4);
            a5 = fmaf(w, __uint_as_float(u.z & 0xffff0000u), a5);
            a6 = fmaf(w, __uint_as_float(u.w << 16), a6);
            a7 = fmaf(w, __uint_as_float(u.w & 0xffff0000u), a7);
        }
    }
    const float4 b0 = *(const float4*)(bias + l * 8);
    const float4 b1v = *(const float4*)(bias + l * 8 + 4);
    a0 = fmaxf(a0 + b0.x, 0.f);  a1 = fmaxf(a1 + b0.y, 0.f);
    a2 = fmaxf(a2 + b0.z, 0.f);  a3 = fmaxf(a3 + b0.w, 0.f);
    a4 = fmaxf(a4 + b1v.x, 0.f); a5 = fmaxf(a5 + b1v.y, 0.f);
    a6 = fmaxf(a6 + b1v.z, 0.f); a7 = fmaxf(a7 + b1v.w, 0.f);
    uint4 p;
    p.x = (unsigned)f2bf(a0) | ((unsigned)f2bf(a1) << 16);
    p.y = (unsigned)f2bf(a2) | ((unsigned)f2bf(a3) << 16);
    p.z = (unsigned)f2bf(a4) | ((unsigned)f2bf(a5) << 16);
    p.w = (unsigned)f2bf(a6) | ((unsigned)f2bf(a7) << 16);
    outv[(size_t)row * 16 + l] = p;   // bf16 row = 16 uint4
}

// ---- graph_sum: gpart[g*SPLIT+p][d] = Sum_{edge chunk} w_e * S1[src_e][d]
// Edges of graph g are CSR-contiguous: [rp[gptr[g]], rp[gptr[g+1]]).
__global__ __launch_bounds__(256)
void graph_sum(const uint4* __restrict__ S1u4, const long long* __restrict__ ep,
               const int* __restrict__ rp, const int* __restrict__ gptr,
               float* __restrict__ gpart) {
    __shared__ float red[16][128];   // 8KB
    int g = blockIdx.x / SPLIT, p = blockIdx.x % SPLIT;
    int e0 = rp[gptr[g]], e1 = rp[gptr[g + 1]];
    int len = e1 - e0;
    int blo = e0 + (int)((long long)len * p / SPLIT);
    int bhi = e0 + (int)((long long)len * (p + 1) / SPLIT);
    int qw = threadIdx.x >> 4;       // 16 quarter-waves
    int l = threadIdx.x & 15;        // dim-octet (8 dims)
    float a0 = 0.f, a1 = 0.f, a2 = 0.f, a3 = 0.f,
          a4 = 0.f, a5 = 0.f, a6 = 0.f, a7 = 0.f;

    for (int t0 = blo + qw * 16; t0 < bhi; t0 += 256) {
        int j = t0 + l;
        long long epk = (j < bhi) ? __builtin_nontemporal_load(ep + j) : 0ll;
        int cnt = min(16, bhi - t0);
#pragma unroll 8
        for (int t = 0; t < cnt; t++) {
            long long ebc = __shfl(epk, t, 16);
            int s = (int)(ebc & 0xffffffffll);
            float w = __uint_as_float((unsigned)((unsigned long long)ebc >> 32));
            uint4 u = S1u4[(size_t)s * 16 + l];
            a0 = fmaf(w, __uint_as_float(u.x << 16), a0);
            a1 = fmaf(w, __uint_as_float(u.x & 0xffff0000u), a1);
            a2 = fmaf(w, __uint_as_float(u.y << 16), a2);
            a3 = fmaf(w, __uint_as_float(u.y & 0xffff0000u), a3);
            a4 = fmaf(w, __uint_as_float(u.z << 16), a4);
            a5 = fmaf(w, __uint_as_float(u.z & 0xffff0000u), a5);
            a6 = fmaf(w, __uint_as_float(u.w << 16), a6);
            a7 = fmaf(w, __uint_as_float(u.w & 0xffff0000u), a7);
        }
    }
    float* rr = &red[qw][l * 8];
    rr[0] = a0; rr[1] = a1; rr[2] = a2; rr[3] = a3;
    rr[4] = a4; rr[5] = a5; rr[6] = a6; rr[7] = a7;
    __syncthreads();
    int d = threadIdx.x;
    if (d < 128) {
        float s = 0.f;
#pragma unroll
        for (int q = 0; q < 16; q++) s += red[q][d];
        gpart[(size_t)(g * SPLIT + p) * 128 + d] = s;
    }
}

// ======================= graph bounds + FF ==================================

__global__ __launch_bounds__(256)
void bounds_kernel(const int* __restrict__ gid, int* __restrict__ ptr, int n) {
    int i = blockIdx.x * 256 + threadIdx.x;
    if (i >= n) return;
    int b = gid[i];
    int a = (i == 0) ? -1 : gid[i - 1];
    for (int g = a + 1; g <= b; g++) ptr[g] = i;
    if (i == n - 1) {
        for (int g = b + 1; g <= G; g++) ptr[g] = n;
    }
}

// pooled[g] = (sum_p gpart) @ W2 / cnt + b2, then 3-layer FF + shortcut + sigmoid
__global__ __launch_bounds__(128)
void ff_kernel(const float* __restrict__ gpart, const int* __restrict__ gptr,
               const float* __restrict__ W2, const float* __restrict__ b2,
               const float* __restrict__ W1, const float* __restrict__ b1,
               const float* __restrict__ Wf2, const float* __restrict__ bf2,
               const float* __restrict__ W3, const float* __restrict__ b3,
               const float* __restrict__ Wsc, const float* __restrict__ bsc,
               float* __restrict__ ffout) {
    __shared__ float gs[D], hx[D], za[D], zb[D];
    int g = blockIdx.x, d = threadIdx.x;
    float s = 0.f;
#pragma unroll
    for (int p = 0; p < SPLIT; p++)
        s += gpart[(size_t)(g * SPLIT + p) * 128 + d];
    gs[d] = s;
    __syncthreads();
    int cnt = gptr[g + 1] - gptr[g];
    s = 0.f;
    for (int k = 0; k < D; k++) s = fmaf(gs[k], W2[k * D + d], s);
    hx[d] = (cnt > 0) ? (s / (float)cnt + b2[d]) : 0.f;
    __syncthreads();
    s = b1[d];
    for (int k = 0; k < D; k++) s = fmaf(hx[k], W1[k * D + d], s);
    za[d] = fmaxf(s, 0.f);
    __syncthreads();
    s = bf2[d];
    for (int k = 0; k < D; k++) s = fmaf(za[k], Wf2[k * D + d], s);
    zb[d] = fmaxf(s, 0.f);
    __syncthreads();
    s = b3[d];
    for (int k = 0; k < D; k++) s = fmaf(zb[k], W3[k * D + d], s);
    float z3 = fmaxf(s, 0.f);
    float sc = bsc[d];
    for (int k = 0; k < D; k++) sc = fmaf(hx[k], Wsc[k * D + d], sc);
    float v = z3 + sc;
    ffout[g * D + d] = 1.f / (1.f + expf(-v));
}

__global__ __launch_bounds__(256)
void scatter_kernel(const float* __restrict__ ffout, const int* __restrict__ gid,
                    float* __restrict__ out, int n) {
    unsigned idx = blockIdx.x * 256u + threadIdx.x;
    unsigned node = idx >> 5;
    if (node >= (unsigned)n) return;
    int d0 = (idx & 31) * 4;
    int g = gid[node];
    *(float4*)(out + (size_t)node * D + d0) = *(const float4*)(ffout + g * D + d0);
}

extern "C" void kernel_launch(void* const* d_in, const int* in_sizes, int n_in,
                              void* d_out, int out_size, void* d_ws, size_t ws_size,
                              hipStream_t stream) {
    const float* feat = (const float*)d_in[0];
    const float* ew   = (const float*)d_in[1];
    const float* W1   = (const float*)d_in[2];
    const float* b1   = (const float*)d_in[3];
    const float* W2   = (const float*)d_in[4];
    const float* b2   = (const float*)d_in[5];
    const float* ffW1 = (const float*)d_in[6];
    const float* ffb1 = (const float*)d_in[7];
    const float* ffW2 = (const float*)d_in[8];
    const float* ffb2 = (const float*)d_in[9];
    const float* ffW3 = (const float*)d_in[10];
    const float* ffb3 = (const float*)d_in[11];
    const float* ffWs = (const float*)d_in[12];
    const float* ffbs = (const float*)d_in[13];
    const int* esrc = (const int*)d_in[14];
    const int* edst = (const int*)d_in[15];
    const int* gid  = (const int*)d_in[16];

    const int N = in_sizes[0] / D;
    const int E = in_sizes[1];
    float* out = (float*)d_out;

    const int rpb = (N + NB - 1) / NB;        // 196 (<=256 required by bucket_sort)
    const int chunk = (E + NBLK - 1) / NBLK;  // edges per scatter block

    // workspace layout
    char* ws = (char*)d_ws;
    int2* ep = (int2*)ws;                                   // E int2 = 12.8MB
    unsigned short* A = (unsigned short*)(ep + E);          // N*128 bf16 = 25.6MB
    // build temporaries alias A (A written only after build completes)
    int2* tmp_sw = (int2*)A;                                // E int2 = 12.8MB
    unsigned short* tmp_lr = (unsigned short*)(tmp_sw + E); // E u16  =  3.2MB
    float* ffo = (float*)(A + (size_t)N * D);               // G*D
    int* gptr = (int*)(ffo + G * D);                        // G+1 (+pad)
    int* row_ptr = gptr + G + 2;                            // N+1
    int* bbase = row_ptr + N + 1;                           // NB+1
    int* bsum = bbase + NB + 1;                             // NB
    int* counts = bsum + NB;                                // NB*NBLK = 1MB
    short* WT1 = (short*)(counts + NB * NBLK);              // 128*128 bf16
    float* gpart = (float*)(WT1 + 128 * 128);               // G*SPLIT*128 = 1MB

    unsigned short* S1 = (unsigned short*)d_out;  // bf16 layer-1 act (front 25.6MB)

    const dim3 blk(256);
    const int nGrid = (N + 255) / 256;
    const int ngroups = (N + 15) / 16;
    const int gemmGrid = (ngroups + 7) / 8;

    // ---- weight transpose+bf16 (tiny)
    prep_wt<<<64, blk, 0, stream>>>(W1, WT1);

    // ---- CSR build (atomic-free radix partition; LDS atomics only)
    radix_count<<<NBLK, blk, 0, stream>>>(edst, counts, E, rpb, chunk);
    radix_scan_rel<<<NB, blk, 0, stream>>>(counts, bsum);
    radix_base<<<1, NB, 0, stream>>>(bsum, bbase, row_ptr, E, N);
    radix_scatter<<<NBLK, blk, 0, stream>>>(esrc, edst, ew, counts, bbase,
                                            tmp_sw, tmp_lr, E, rpb, chunk);
    bucket_sort<<<NB, blk, 0, stream>>>(tmp_lr, tmp_sw, bbase, ep, row_ptr, N, rpb);

    // ---- graph boundaries from sorted gid
    bounds_kernel<<<nGrid, blk, 0, stream>>>(gid, gptr, N);

    // ---- pipeline
    // A1 = feat @ W1 (bf16)
    gemm_mfma_f32in<<<gemmGrid, blk, 0, stream>>>(feat, WT1, (short*)A, N);
    // S1 = bf16(relu(spmm(A1) + b1))
    spmm_csr_fused<<<(N + 15) / 16, blk, 0, stream>>>((const uint4*)A, (const long long*)ep,
                                                      row_ptr, b1, (uint4*)S1, N);
    // gpart = per-graph partial sums of w_e * S1[src_e]
    graph_sum<<<G * SPLIT, blk, 0, stream>>>((const uint4*)S1, (const long long*)ep,
                                             row_ptr, gptr, gpart);
    // pooled = (sum gpart) @ W2 / cnt + b2; FF MLP + shortcut + sigmoid
    ff_kernel<<<G, 128, 0, stream>>>(gpart, gptr, W2, b2,
                                     ffW1, ffb1, ffW2, ffb2,
                                     ffW3, ffb3, ffWs, ffbs, ffo);
    // out[n] = ffo[graph_id[n]]
    scatter_kernel<<<(int)(((size_t)N * 32 + 255) / 256), blk, 0, stream>>>(ffo, gid, out, N);
}

// Round 13
// 216.563 us; speedup vs baseline: 1.5750x; 1.1999x over previous
//
#include <hip/hip_runtime.h>
#include <math.h>

// ---------------------------------------------------------------------------
// Encoder: GCN(2 layers) + per-graph mean pool + FF MLP on pooled rows + sigmoid
// N=100000 nodes, E=1600000 edges, D=128, G=256 graphs (graph_id sorted)
// Round 13: fp8-e4m3 gather tables (both A1 and S1).
//   Post-r12 both gather passes feed averaging reductions (spmm sums ~16
//   edges; graph_sum averages ~6250 edges/graph) => fp8's ~4% per-element
//   error washes out (~0.05% on pooled). Rows 256B->128B: logical gather
//   traffic 409->205MB/pass, table 25.6->12.8MB (better L2 residency).
//   HW cvt: v_cvt_pk_fp8_f32 (pack) / v_cvt_pk_f32_fp8 (unpack).
// ---------------------------------------------------------------------------

#define D 128
#define G 256
#define NB 512     // dst buckets (rows-per-bucket = ceil(N/NB) = 196 <= 256)
#define NBLK 512   // scatter blocks (each owns a contiguous edge chunk)
#define SPLIT 8    // partial-sum blocks per graph in graph_sum (deterministic)

typedef __attribute__((ext_vector_type(8))) short bf16x8;
typedef __attribute__((ext_vector_type(4))) float f32x4;
typedef __attribute__((ext_vector_type(2))) float f32x2;

__device__ __forceinline__ unsigned short f2bf(float f) {
    unsigned u = __float_as_uint(f);
    unsigned r = (u + 0x7fffu + ((u >> 16) & 1u)) >> 16;   // round-nearest-even
    return (unsigned short)r;
}

// pack 4 f32 -> 4 fp8 e4m3 bytes (byte i = value i)
__device__ __forceinline__ unsigned pack_fp8x4(float a, float b, float c, float d) {
    int v = __builtin_amdgcn_cvt_pk_fp8_f32(a, b, 0, false);   // bytes 0,1
    v = __builtin_amdgcn_cvt_pk_fp8_f32(c, d, v, true);        // bytes 2,3
    return (unsigned)v;
}

// ---- one-time: WT1[c][k] = bf16(W1[k][c])  (128x128)
__global__ __launch_bounds__(256)
void prep_wt(const float* __restrict__ W, short* __restrict__ WT) {
    int idx = blockIdx.x * 256 + threadIdx.x;
    if (idx >= 128 * 128) return;
    int k = idx >> 7, c = idx & 127;
    WT[c * 128 + k] = (short)f2bf(W[k * 128 + c]);
}

// ---- MFMA GEMM (fp32 input): Y_fp8 = X_f32 @ W   (WT = W^T bf16)
__global__ __launch_bounds__(256, 2)
void gemm_mfma_f32in(const float* __restrict__ X, const short* __restrict__ WT,
                     unsigned char* __restrict__ Y, int nrows) {
    const int lane = threadIdx.x & 63;
    const int lr = lane & 15;
    const int lq = lane >> 4;
    const int wid = blockIdx.x * 4 + (threadIdx.x >> 6);
    const int nwaves = gridDim.x * 4;
    const int ngroups = (nrows + 15) >> 4;

    bf16x8 wf[8][4];
#pragma unroll
    for (int mt = 0; mt < 8; mt++)
#pragma unroll
        for (int ks = 0; ks < 4; ks++)
            wf[mt][ks] = *(const bf16x8*)(WT + (mt * 16 + lr) * 128 + ks * 32 + lq * 8);

    for (int g = wid; g < ngroups; g += nwaves) {
        int node = g * 16 + lr;
        int nrow = min(node, nrows - 1);
        const float* xp = X + (size_t)nrow * D + lq * 8;
        f32x4 acc[8];
#pragma unroll
        for (int mt = 0; mt < 8; mt++) acc[mt] = (f32x4){0.f, 0.f, 0.f, 0.f};

#pragma unroll
        for (int ks = 0; ks < 4; ks++) {
            float4 v0 = *(const float4*)(xp + ks * 32);
            float4 v1 = *(const float4*)(xp + ks * 32 + 4);
            bf16x8 xb;
            xb[0] = (short)f2bf(v0.x);
            xb[1] = (short)f2bf(v0.y);
            xb[2] = (short)f2bf(v0.z);
            xb[3] = (short)f2bf(v0.w);
            xb[4] = (short)f2bf(v1.x);
            xb[5] = (short)f2bf(v1.y);
            xb[6] = (short)f2bf(v1.z);
            xb[7] = (short)f2bf(v1.w);
#pragma unroll
            for (int mt = 0; mt < 8; mt++)
                acc[mt] = __builtin_amdgcn_mfma_f32_16x16x32_bf16(wf[mt][ks], xb, acc[mt], 0, 0, 0);
        }

        if (node < nrows) {
            unsigned char* yp = Y + (size_t)node * D + lq * 4;
#pragma unroll
            for (int mt = 0; mt < 8; mt++) {
                unsigned o = pack_fp8x4(acc[mt][0], acc[mt][1], acc[mt][2], acc[mt][3]);
                *(unsigned*)(yp + mt * 16) = o;
            }
        }
    }
}

// ============== CSR build: atomic-free radix partition + bucket sort ========

__global__ __launch_bounds__(256)
void radix_count(const int* __restrict__ dst, int* __restrict__ counts,
                 int ne, int rpb, int chunk) {
    __shared__ int h[NB];
    for (int i = threadIdx.x; i < NB; i += 256) h[i] = 0;
    __syncthreads();
    int b = blockIdx.x;
    int lo = b * chunk, hi = min(lo + chunk, ne);
    for (int e = lo + threadIdx.x; e < hi; e += 256)
        atomicAdd(&h[dst[e] / rpb], 1);
    __syncthreads();
    for (int k = threadIdx.x; k < NB; k += 256)
        counts[k * NBLK + b] = h[k];
}

__global__ __launch_bounds__(256)
void radix_scan_rel(int* __restrict__ counts, int* __restrict__ bsum) {
    __shared__ int s[256];
    int k = blockIdx.x, t = threadIdx.x;
    int base = k * NBLK + t * 2;
    int v0 = counts[base], v1 = counts[base + 1];
    int sum = v0 + v1;
    s[t] = sum;
    __syncthreads();
    for (int off = 1; off < 256; off <<= 1) {
        int x = (t >= off) ? s[t - off] : 0;
        __syncthreads();
        s[t] += x;
        __syncthreads();
    }
    int ex = s[t] - sum;
    counts[base] = ex;
    counts[base + 1] = ex + v0;
    if (t == 255) bsum[k] = s[255];
}

__global__ __launch_bounds__(NB)
void radix_base(const int* __restrict__ bsum, int* __restrict__ bbase,
                int* __restrict__ row_ptr, int ne, int n) {
    __shared__ int s[NB];
    int t = threadIdx.x;
    int v = bsum[t];
    s[t] = v;
    __syncthreads();
    for (int off = 1; off < NB; off <<= 1) {
        int x = (t >= off) ? s[t - off] : 0;
        __syncthreads();
        s[t] += x;
        __syncthreads();
    }
    bbase[t + 1] = s[t];
    if (t == 0) { bbase[0] = 0; row_ptr[n] = ne; }
}

__global__ __launch_bounds__(256)
void radix_scatter(const int* __restrict__ src, const int* __restrict__ dst,
                   const float* __restrict__ ew,
                   const int* __restrict__ counts, const int* __restrict__ bbase,
                   int2* __restrict__ tmp_sw, unsigned short* __restrict__ tmp_lr,
                   int ne, int rpb, int chunk) {
    __shared__ int cur[NB];
    int b = blockIdx.x;
    for (int k = threadIdx.x; k < NB; k += 256)
        cur[k] = bbase[k] + counts[k * NBLK + b];
    __syncthreads();
    int lo = b * chunk, hi = min(lo + chunk, ne);
    for (int e = lo + threadIdx.x; e < hi; e += 256) {
        int d = dst[e];
        int k = d / rpb;
        int pos = atomicAdd(&cur[k], 1);          // LDS atomic
        tmp_sw[pos] = make_int2(src[e], __float_as_int(ew[e]));
        tmp_lr[pos] = (unsigned short)(d - k * rpb);
    }
}

__global__ __launch_bounds__(256)
void bucket_sort(const unsigned short* __restrict__ tmp_lr,
                 const int2* __restrict__ tmp_sw,
                 const int* __restrict__ bbase, int2* __restrict__ ep,
                 int* __restrict__ row_ptr, int n, int rpb) {
    __shared__ int cnt[256], scn[256], cur[256];
    int b = blockIdx.x, t = threadIdx.x;
    int e0 = bbase[b], e1 = bbase[b + 1];
    int r0 = b * rpb;
    cnt[t] = 0;
    __syncthreads();
    for (int i = e0 + t; i < e1; i += 256)
        atomicAdd(&cnt[tmp_lr[i]], 1);
    __syncthreads();
    int v = cnt[t];
    scn[t] = v;
    __syncthreads();
    for (int off = 1; off < 256; off <<= 1) {
        int x = (t >= off) ? scn[t - off] : 0;
        __syncthreads();
        scn[t] += x;
        __syncthreads();
    }
    int ex = scn[t] - v;
    cur[t] = ex;
    int grow = r0 + t;
    if (t < rpb && grow < n) row_ptr[grow] = e0 + ex;
    __syncthreads();
    for (int i = e0 + t; i < e1; i += 256) {
        int r = tmp_lr[i];
        int pos = e0 + atomicAdd(&cur[r], 1);     // LDS atomic
        ep[pos] = tmp_sw[i];
    }
}

// ---- Layer-1 SpMM: quarter-wave per row (16 lanes x uint2 = 128B fp8 row);
// fused relu(.+b1) -> fp8 out.
__global__ __launch_bounds__(256)
void spmm_csr_fused(const uint2* __restrict__ Xf8, const long long* __restrict__ ep,
                    const int* __restrict__ rp, const float* __restrict__ bias,
                    uint2* __restrict__ outv, int nrows) {
    int row = blockIdx.x * 16 + (threadIdx.x >> 4);
    if (row >= nrows) return;
    int l = threadIdx.x & 15;             // dim-octet index (8 dims)
    int beg = rp[row], end = rp[row + 1];
    float a0 = 0.f, a1 = 0.f, a2 = 0.f, a3 = 0.f,
          a4 = 0.f, a5 = 0.f, a6 = 0.f, a7 = 0.f;

    for (int t0 = beg; t0 < end; t0 += 16) {
        int j = t0 + l;
        long long epk = (j < end) ? __builtin_nontemporal_load(ep + j) : 0ll;
        int cnt = min(16, end - t0);
#pragma unroll 8
        for (int t = 0; t < cnt; t++) {
            long long ebc = __shfl(epk, t, 16);
            int s = (int)(ebc & 0xffffffffll);
            float w = __uint_as_float((unsigned)((unsigned long long)ebc >> 32));
            uint2 u = Xf8[(size_t)s * 16 + l];
            f32x2 p0 = __builtin_amdgcn_cvt_pk_f32_fp8((int)u.x, false);
            f32x2 p1 = __builtin_amdgcn_cvt_pk_f32_fp8((int)u.x, true);
            f32x2 p2 = __builtin_amdgcn_cvt_pk_f32_fp8((int)u.y, false);
            f32x2 p3 = __builtin_amdgcn_cvt_pk_f32_fp8((int)u.y, true);
            a0 = fmaf(w, p0[0], a0);
            a1 = fmaf(w, p0[1], a1);
            a2 = fmaf(w, p1[0], a2);
            a3 = fmaf(w, p1[1], a3);
            a4 = fmaf(w, p2[0], a4);
            a5 = fmaf(w, p2[1], a5);
            a6 = fmaf(w, p3[0], a6);
            a7 = fmaf(w, p3[1], a7);
        }
    }
    const float4 b0 = *(const float4*)(bias + l * 8);
    const float4 b1v = *(const float4*)(bias + l * 8 + 4);
    a0 = fmaxf(a0 + b0.x, 0.f);  a1 = fmaxf(a1 + b0.y, 0.f);
    a2 = fmaxf(a2 + b0.z, 0.f);  a3 = fmaxf(a3 + b0.w, 0.f);
    a4 = fmaxf(a4 + b1v.x, 0.f); a5 = fmaxf(a5 + b1v.y, 0.f);
    a6 = fmaxf(a6 + b1v.z, 0.f); a7 = fmaxf(a7 + b1v.w, 0.f);
    uint2 p;
    p.x = pack_fp8x4(a0, a1, a2, a3);
    p.y = pack_fp8x4(a4, a5, a6, a7);
    outv[(size_t)row * 16 + l] = p;   // fp8 row = 128B = 16 uint2
}

// ---- graph_sum: gpart[g*SPLIT+p][d] = Sum_{edge chunk} w_e * S1[src_e][d]
// Edges of graph g are CSR-contiguous: [rp[gptr[g]], rp[gptr[g+1]]).
__global__ __launch_bounds__(256)
void graph_sum(const uint2* __restrict__ S1f8, const long long* __restrict__ ep,
               const int* __restrict__ rp, const int* __restrict__ gptr,
               float* __restrict__ gpart) {
    __shared__ float red[16][128];   // 8KB
    int g = blockIdx.x / SPLIT, p = blockIdx.x % SPLIT;
    int e0 = rp[gptr[g]], e1 = rp[gptr[g + 1]];
    int len = e1 - e0;
    int blo = e0 + (int)((long long)len * p / SPLIT);
    int bhi = e0 + (int)((long long)len * (p + 1) / SPLIT);
    int qw = threadIdx.x >> 4;       // 16 quarter-waves
    int l = threadIdx.x & 15;        // dim-octet (8 dims)
    float a0 = 0.f, a1 = 0.f, a2 = 0.f, a3 = 0.f,
          a4 = 0.f, a5 = 0.f, a6 = 0.f, a7 = 0.f;

    for (int t0 = blo + qw * 16; t0 < bhi; t0 += 256) {
        int j = t0 + l;
        long long epk = (j < bhi) ? __builtin_nontemporal_load(ep + j) : 0ll;
        int cnt = min(16, bhi - t0);
#pragma unroll 8
        for (int t = 0; t < cnt; t++) {
            long long ebc = __shfl(epk, t, 16);
            int s = (int)(ebc & 0xffffffffll);
            float w = __uint_as_float((unsigned)((unsigned long long)ebc >> 32));
            uint2 u = S1f8[(size_t)s * 16 + l];
            f32x2 p0 = __builtin_amdgcn_cvt_pk_f32_fp8((int)u.x, false);
            f32x2 p1 = __builtin_amdgcn_cvt_pk_f32_fp8((int)u.x, true);
            f32x2 p2 = __builtin_amdgcn_cvt_pk_f32_fp8((int)u.y, false);
            f32x2 p3 = __builtin_amdgcn_cvt_pk_f32_fp8((int)u.y, true);
            a0 = fmaf(w, p0[0], a0);
            a1 = fmaf(w, p0[1], a1);
            a2 = fmaf(w, p1[0], a2);
            a3 = fmaf(w, p1[1], a3);
            a4 = fmaf(w, p2[0], a4);
            a5 = fmaf(w, p2[1], a5);
            a6 = fmaf(w, p3[0], a6);
            a7 = fmaf(w, p3[1], a7);
        }
    }
    float* rr = &red[qw][l * 8];
    rr[0] = a0; rr[1] = a1; rr[2] = a2; rr[3] = a3;
    rr[4] = a4; rr[5] = a5; rr[6] = a6; rr[7] = a7;
    __syncthreads();
    int d = threadIdx.x;
    if (d < 128) {
        float s = 0.f;
#pragma unroll
        for (int q = 0; q < 16; q++) s += red[q][d];
        gpart[(size_t)(g * SPLIT + p) * 128 + d] = s;
    }
}

// ======================= graph bounds + FF ==================================

__global__ __launch_bounds__(256)
void bounds_kernel(const int* __restrict__ gid, int* __restrict__ ptr, int n) {
    int i = blockIdx.x * 256 + threadIdx.x;
    if (i >= n) return;
    int b = gid[i];
    int a = (i == 0) ? -1 : gid[i - 1];
    for (int g = a + 1; g <= b; g++) ptr[g] = i;
    if (i == n - 1) {
        for (int g = b + 1; g <= G; g++) ptr[g] = n;
    }
}

// pooled[g] = (sum_p gpart) @ W2 / cnt + b2, then 3-layer FF + shortcut + sigmoid
__global__ __launch_bounds__(128)
void ff_kernel(const float* __restrict__ gpart, const int* __restrict__ gptr,
               const float* __restrict__ W2, const float* __restrict__ b2,
               const float* __restrict__ W1, const float* __restrict__ b1,
               const float* __restrict__ Wf2, const float* __restrict__ bf2,
               const float* __restrict__ W3, const float* __restrict__ b3,
               const float* __restrict__ Wsc, const float* __restrict__ bsc,
               float* __restrict__ ffout) {
    __shared__ float gs[D], hx[D], za[D], zb[D];
    int g = blockIdx.x, d = threadIdx.x;
    float s = 0.f;
#pragma unroll
    for (int p = 0; p < SPLIT; p++)
        s += gpart[(size_t)(g * SPLIT + p) * 128 + d];
    gs[d] = s;
    __syncthreads();
    int cnt = gptr[g + 1] - gptr[g];
    s = 0.f;
    for (int k = 0; k < D; k++) s = fmaf(gs[k], W2[k * D + d], s);
    hx[d] = (cnt > 0) ? (s / (float)cnt + b2[d]) : 0.f;
    __syncthreads();
    s = b1[d];
    for (int k = 0; k < D; k++) s = fmaf(hx[k], W1[k * D + d], s);
    za[d] = fmaxf(s, 0.f);
    __syncthreads();
    s = bf2[d];
    for (int k = 0; k < D; k++) s = fmaf(za[k], Wf2[k * D + d], s);
    zb[d] = fmaxf(s, 0.f);
    __syncthreads();
    s = b3[d];
    for (int k = 0; k < D; k++) s = fmaf(zb[k], W3[k * D + d], s);
    float z3 = fmaxf(s, 0.f);
    float sc = bsc[d];
    for (int k = 0; k < D; k++) sc = fmaf(hx[k], Wsc[k * D + d], sc);
    float v = z3 + sc;
    ffout[g * D + d] = 1.f / (1.f + expf(-v));
}

__global__ __launch_bounds__(256)
void scatter_kernel(const float* __restrict__ ffout, const int* __restrict__ gid,
                    float* __restrict__ out, int n) {
    unsigned idx = blockIdx.x * 256u + threadIdx.x;
    unsigned node = idx >> 5;
    if (node >= (unsigned)n) return;
    int d0 = (idx & 31) * 4;
    int g = gid[node];
    *(float4*)(out + (size_t)node * D + d0) = *(const float4*)(ffout + g * D + d0);
}

extern "C" void kernel_launch(void* const* d_in, const int* in_sizes, int n_in,
                              void* d_out, int out_size, void* d_ws, size_t ws_size,
                              hipStream_t stream) {
    const float* feat = (const float*)d_in[0];
    const float* ew   = (const float*)d_in[1];
    const float* W1   = (const float*)d_in[2];
    const float* b1   = (const float*)d_in[3];
    const float* W2   = (const float*)d_in[4];
    const float* b2   = (const float*)d_in[5];
    const float* ffW1 = (const float*)d_in[6];
    const float* ffb1 = (const float*)d_in[7];
    const float* ffW2 = (const float*)d_in[8];
    const float* ffb2 = (const float*)d_in[9];
    const float* ffW3 = (const float*)d_in[10];
    const float* ffb3 = (const float*)d_in[11];
    const float* ffWs = (const float*)d_in[12];
    const float* ffbs = (const float*)d_in[13];
    const int* esrc = (const int*)d_in[14];
    const int* edst = (const int*)d_in[15];
    const int* gid  = (const int*)d_in[16];

    const int N = in_sizes[0] / D;
    const int E = in_sizes[1];
    float* out = (float*)d_out;

    const int rpb = (N + NB - 1) / NB;        // 196 (<=256 required by bucket_sort)
    const int chunk = (E + NBLK - 1) / NBLK;  // edges per scatter block

    // workspace layout (no aliasing; ~44MB total)
    char* ws = (char*)d_ws;
    int2* ep = (int2*)ws;                                   // E int2 = 12.8MB
    unsigned char* A = (unsigned char*)(ep + E);            // N*128 fp8 = 12.8MB
    int2* tmp_sw = (int2*)(A + (size_t)N * D);              // E int2 = 12.8MB
    unsigned short* tmp_lr = (unsigned short*)(tmp_sw + E); // E u16  =  3.2MB
    float* ffo = (float*)(tmp_lr + E);                      // G*D
    int* gptr = (int*)(ffo + G * D);                        // G+1 (+pad)
    int* row_ptr = gptr + G + 2;                            // N+1
    int* bbase = row_ptr + N + 1;                           // NB+1
    int* bsum = bbase + NB + 1;                             // NB
    int* counts = bsum + NB;                                // NB*NBLK = 1MB
    short* WT1 = (short*)(counts + NB * NBLK);              // 128*128 bf16
    float* gpart = (float*)(WT1 + 128 * 128);               // G*SPLIT*128 = 1MB

    unsigned char* S1 = (unsigned char*)d_out;  // fp8 layer-1 act (front 12.8MB)

    const dim3 blk(256);
    const int nGrid = (N + 255) / 256;
    const int ngroups = (N + 15) / 16;
    const int gemmGrid = (ngroups + 7) / 8;

    // ---- weight transpose+bf16 (tiny)
    prep_wt<<<64, blk, 0, stream>>>(W1, WT1);

    // ---- CSR build (atomic-free radix partition; LDS atomics only)
    radix_count<<<NBLK, blk, 0, stream>>>(edst, counts, E, rpb, chunk);
    radix_scan_rel<<<NB, blk, 0, stream>>>(counts, bsum);
    radix_base<<<1, NB, 0, stream>>>(bsum, bbase, row_ptr, E, N);
    radix_scatter<<<NBLK, blk, 0, stream>>>(esrc, edst, ew, counts, bbase,
                                            tmp_sw, tmp_lr, E, rpb, chunk);
    bucket_sort<<<NB, blk, 0, stream>>>(tmp_lr, tmp_sw, bbase, ep, row_ptr, N, rpb);

    // ---- graph boundaries from sorted gid
    bounds_kernel<<<nGrid, blk, 0, stream>>>(gid, gptr, N);

    // ---- pipeline
    // A1 = fp8(feat @ W1)
    gemm_mfma_f32in<<<gemmGrid, blk, 0, stream>>>(feat, WT1, A, N);
    // S1 = fp8(relu(spmm(A1) + b1))
    spmm_csr_fused<<<(N + 15) / 16, blk, 0, stream>>>((const uint2*)A, (const long long*)ep,
                                                      row_ptr, b1, (uint2*)S1, N);
    // gpart = per-graph partial sums of w_e * S1[src_e]
    graph_sum<<<G * SPLIT, blk, 0, stream>>>((const uint2*)S1, (const long long*)ep,
                                             row_ptr, gptr, gpart);
    // pooled = (sum gpart) @ W2 / cnt + b2; FF MLP + shortcut + sigmoid
    ff_kernel<<<G, 128, 0, stream>>>(gpart, gptr, W2, b2,
                                     ffW1, ffb1, ffW2, ffb2,
                                     ffW3, ffb3, ffWs, ffbs, ffo);
    // out[n] = ffo[graph_id[n]]
    scatter_kernel<<<(int)(((size_t)N * 32 + 255) / 256), blk, 0, stream>>>(ffo, gid, out, N);
}

// Round 14
// 197.009 us; speedup vs baseline: 1.7313x; 1.0993x over previous
//
#include <hip/hip_runtime.h>
#include <math.h>

// ---------------------------------------------------------------------------
// Encoder: GCN(2 layers) + per-graph mean pool + FF MLP on pooled rows + sigmoid
// N=100000 nodes, E=1600000 edges, D=128, G=256 graphs (graph_id sorted)
// Round 14: radix_scatter write-amplification fix.
//   r13 counters: radix_scatter WRITE=85MB for 16MB logical (two scattered
//   arrays, ~6-edge runs => partial-line evictions), 60us, top dispatch.
//   Now ONE 8B record per edge: packed = src | (local_row << 20)  (src<2^17,
//   lr<196<2^8) + fp32 weight. Single aligned int2 store; tmp_lr deleted.
// ---------------------------------------------------------------------------

#define D 128
#define G 256
#define NB 512     // dst buckets (rows-per-bucket = ceil(N/NB) = 196 <= 256)
#define NBLK 512   // scatter blocks (each owns a contiguous edge chunk)
#define SPLIT 8    // partial-sum blocks per graph in graph_sum (deterministic)

typedef __attribute__((ext_vector_type(8))) short bf16x8;
typedef __attribute__((ext_vector_type(4))) float f32x4;
typedef __attribute__((ext_vector_type(2))) float f32x2;

__device__ __forceinline__ unsigned short f2bf(float f) {
    unsigned u = __float_as_uint(f);
    unsigned r = (u + 0x7fffu + ((u >> 16) & 1u)) >> 16;   // round-nearest-even
    return (unsigned short)r;
}

// pack 4 f32 -> 4 fp8 e4m3 bytes (byte i = value i)
__device__ __forceinline__ unsigned pack_fp8x4(float a, float b, float c, float d) {
    int v = __builtin_amdgcn_cvt_pk_fp8_f32(a, b, 0, false);   // bytes 0,1
    v = __builtin_amdgcn_cvt_pk_fp8_f32(c, d, v, true);        // bytes 2,3
    return (unsigned)v;
}

// ---- one-time: WT1[c][k] = bf16(W1[k][c])  (128x128)
__global__ __launch_bounds__(256)
void prep_wt(const float* __restrict__ W, short* __restrict__ WT) {
    int idx = blockIdx.x * 256 + threadIdx.x;
    if (idx >= 128 * 128) return;
    int k = idx >> 7, c = idx & 127;
    WT[c * 128 + k] = (short)f2bf(W[k * 128 + c]);
}

// ---- MFMA GEMM (fp32 input): Y_fp8 = X_f32 @ W   (WT = W^T bf16)
__global__ __launch_bounds__(256, 2)
void gemm_mfma_f32in(const float* __restrict__ X, const short* __restrict__ WT,
                     unsigned char* __restrict__ Y, int nrows) {
    const int lane = threadIdx.x & 63;
    const int lr = lane & 15;
    const int lq = lane >> 4;
    const int wid = blockIdx.x * 4 + (threadIdx.x >> 6);
    const int nwaves = gridDim.x * 4;
    const int ngroups = (nrows + 15) >> 4;

    bf16x8 wf[8][4];
#pragma unroll
    for (int mt = 0; mt < 8; mt++)
#pragma unroll
        for (int ks = 0; ks < 4; ks++)
            wf[mt][ks] = *(const bf16x8*)(WT + (mt * 16 + lr) * 128 + ks * 32 + lq * 8);

    for (int g = wid; g < ngroups; g += nwaves) {
        int node = g * 16 + lr;
        int nrow = min(node, nrows - 1);
        const float* xp = X + (size_t)nrow * D + lq * 8;
        f32x4 acc[8];
#pragma unroll
        for (int mt = 0; mt < 8; mt++) acc[mt] = (f32x4){0.f, 0.f, 0.f, 0.f};

#pragma unroll
        for (int ks = 0; ks < 4; ks++) {
            float4 v0 = *(const float4*)(xp + ks * 32);
            float4 v1 = *(const float4*)(xp + ks * 32 + 4);
            bf16x8 xb;
            xb[0] = (short)f2bf(v0.x);
            xb[1] = (short)f2bf(v0.y);
            xb[2] = (short)f2bf(v0.z);
            xb[3] = (short)f2bf(v0.w);
            xb[4] = (short)f2bf(v1.x);
            xb[5] = (short)f2bf(v1.y);
            xb[6] = (short)f2bf(v1.z);
            xb[7] = (short)f2bf(v1.w);
#pragma unroll
            for (int mt = 0; mt < 8; mt++)
                acc[mt] = __builtin_amdgcn_mfma_f32_16x16x32_bf16(wf[mt][ks], xb, acc[mt], 0, 0, 0);
        }

        if (node < nrows) {
            unsigned char* yp = Y + (size_t)node * D + lq * 4;
#pragma unroll
            for (int mt = 0; mt < 8; mt++) {
                unsigned o = pack_fp8x4(acc[mt][0], acc[mt][1], acc[mt][2], acc[mt][3]);
                *(unsigned*)(yp + mt * 16) = o;
            }
        }
    }
}

// ============== CSR build: atomic-free radix partition + bucket sort ========

__global__ __launch_bounds__(256)
void radix_count(const int* __restrict__ dst, int* __restrict__ counts,
                 int ne, int rpb, int chunk) {
    __shared__ int h[NB];
    for (int i = threadIdx.x; i < NB; i += 256) h[i] = 0;
    __syncthreads();
    int b = blockIdx.x;
    int lo = b * chunk, hi = min(lo + chunk, ne);
    for (int e = lo + threadIdx.x; e < hi; e += 256)
        atomicAdd(&h[dst[e] / rpb], 1);
    __syncthreads();
    for (int k = threadIdx.x; k < NB; k += 256)
        counts[k * NBLK + b] = h[k];
}

__global__ __launch_bounds__(256)
void radix_scan_rel(int* __restrict__ counts, int* __restrict__ bsum) {
    __shared__ int s[256];
    int k = blockIdx.x, t = threadIdx.x;
    int base = k * NBLK + t * 2;
    int v0 = counts[base], v1 = counts[base + 1];
    int sum = v0 + v1;
    s[t] = sum;
    __syncthreads();
    for (int off = 1; off < 256; off <<= 1) {
        int x = (t >= off) ? s[t - off] : 0;
        __syncthreads();
        s[t] += x;
        __syncthreads();
    }
    int ex = s[t] - sum;
    counts[base] = ex;
    counts[base + 1] = ex + v0;
    if (t == 255) bsum[k] = s[255];
}

__global__ __launch_bounds__(NB)
void radix_base(const int* __restrict__ bsum, int* __restrict__ bbase,
                int* __restrict__ row_ptr, int ne, int n) {
    __shared__ int s[NB];
    int t = threadIdx.x;
    int v = bsum[t];
    s[t] = v;
    __syncthreads();
    for (int off = 1; off < NB; off <<= 1) {
        int x = (t >= off) ? s[t - off] : 0;
        __syncthreads();
        s[t] += x;
        __syncthreads();
    }
    bbase[t + 1] = s[t];
    if (t == 0) { bbase[0] = 0; row_ptr[n] = ne; }
}

// ONE 8B record per edge: (src | lr<<20, w_fp32). src<2^20, lr<256.
__global__ __launch_bounds__(256)
void radix_scatter(const int* __restrict__ src, const int* __restrict__ dst,
                   const float* __restrict__ ew,
                   const int* __restrict__ counts, const int* __restrict__ bbase,
                   int2* __restrict__ tmp_p, int ne, int rpb, int chunk) {
    __shared__ int cur[NB];
    int b = blockIdx.x;
    for (int k = threadIdx.x; k < NB; k += 256)
        cur[k] = bbase[k] + counts[k * NBLK + b];
    __syncthreads();
    int lo = b * chunk, hi = min(lo + chunk, ne);
    for (int e = lo + threadIdx.x; e < hi; e += 256) {
        int d = dst[e];
        int k = d / rpb;
        int pos = atomicAdd(&cur[k], 1);          // LDS atomic
        tmp_p[pos] = make_int2(src[e] | ((d - k * rpb) << 20), __float_as_int(ew[e]));
    }
}

__global__ __launch_bounds__(256)
void bucket_sort(const int2* __restrict__ tmp_p,
                 const int* __restrict__ bbase, int2* __restrict__ ep,
                 int* __restrict__ row_ptr, int n, int rpb) {
    __shared__ int cnt[256], scn[256], cur[256];
    int b = blockIdx.x, t = threadIdx.x;
    int e0 = bbase[b], e1 = bbase[b + 1];
    int r0 = b * rpb;
    cnt[t] = 0;
    __syncthreads();
    for (int i = e0 + t; i < e1; i += 256)
        atomicAdd(&cnt[(unsigned)tmp_p[i].x >> 20], 1);
    __syncthreads();
    int v = cnt[t];
    scn[t] = v;
    __syncthreads();
    for (int off = 1; off < 256; off <<= 1) {
        int x = (t >= off) ? scn[t - off] : 0;
        __syncthreads();
        scn[t] += x;
        __syncthreads();
    }
    int ex = scn[t] - v;
    cur[t] = ex;
    int grow = r0 + t;
    if (t < rpb && grow < n) row_ptr[grow] = e0 + ex;
    __syncthreads();
    for (int i = e0 + t; i < e1; i += 256) {
        int2 rec = tmp_p[i];
        int r = (unsigned)rec.x >> 20;
        int pos = e0 + atomicAdd(&cur[r], 1);     // LDS atomic
        ep[pos] = make_int2(rec.x & 0xFFFFF, rec.y);
    }
}

// ---- Layer-1 SpMM: quarter-wave per row (16 lanes x uint2 = 128B fp8 row);
// fused relu(.+b1) -> fp8 out.
__global__ __launch_bounds__(256)
void spmm_csr_fused(const uint2* __restrict__ Xf8, const long long* __restrict__ ep,
                    const int* __restrict__ rp, const float* __restrict__ bias,
                    uint2* __restrict__ outv, int nrows) {
    int row = blockIdx.x * 16 + (threadIdx.x >> 4);
    if (row >= nrows) return;
    int l = threadIdx.x & 15;             // dim-octet index (8 dims)
    int beg = rp[row], end = rp[row + 1];
    float a0 = 0.f, a1 = 0.f, a2 = 0.f, a3 = 0.f,
          a4 = 0.f, a5 = 0.f, a6 = 0.f, a7 = 0.f;

    for (int t0 = beg; t0 < end; t0 += 16) {
        int j = t0 + l;
        long long epk = (j < end) ? __builtin_nontemporal_load(ep + j) : 0ll;
        int cnt = min(16, end - t0);
#pragma unroll 8
        for (int t = 0; t < cnt; t++) {
            long long ebc = __shfl(epk, t, 16);
            int s = (int)(ebc & 0xffffffffll);
            float w = __uint_as_float((unsigned)((unsigned long long)ebc >> 32));
            uint2 u = Xf8[(size_t)s * 16 + l];
            f32x2 p0 = __builtin_amdgcn_cvt_pk_f32_fp8((int)u.x, false);
            f32x2 p1 = __builtin_amdgcn_cvt_pk_f32_fp8((int)u.x, true);
            f32x2 p2 = __builtin_amdgcn_cvt_pk_f32_fp8((int)u.y, false);
            f32x2 p3 = __builtin_amdgcn_cvt_pk_f32_fp8((int)u.y, true);
            a0 = fmaf(w, p0[0], a0);
            a1 = fmaf(w, p0[1], a1);
            a2 = fmaf(w, p1[0], a2);
            a3 = fmaf(w, p1[1], a3);
            a4 = fmaf(w, p2[0], a4);
            a5 = fmaf(w, p2[1], a5);
            a6 = fmaf(w, p3[0], a6);
            a7 = fmaf(w, p3[1], a7);
        }
    }
    const float4 b0 = *(const float4*)(bias + l * 8);
    const float4 b1v = *(const float4*)(bias + l * 8 + 4);
    a0 = fmaxf(a0 + b0.x, 0.f);  a1 = fmaxf(a1 + b0.y, 0.f);
    a2 = fmaxf(a2 + b0.z, 0.f);  a3 = fmaxf(a3 + b0.w, 0.f);
    a4 = fmaxf(a4 + b1v.x, 0.f); a5 = fmaxf(a5 + b1v.y, 0.f);
    a6 = fmaxf(a6 + b1v.z, 0.f); a7 = fmaxf(a7 + b1v.w, 0.f);
    uint2 p;
    p.x = pack_fp8x4(a0, a1, a2, a3);
    p.y = pack_fp8x4(a4, a5, a6, a7);
    outv[(size_t)row * 16 + l] = p;   // fp8 row = 128B = 16 uint2
}

// ---- graph_sum: gpart[g*SPLIT+p][d] = Sum_{edge chunk} w_e * S1[src_e][d]
__global__ __launch_bounds__(256)
void graph_sum(const uint2* __restrict__ S1f8, const long long* __restrict__ ep,
               const int* __restrict__ rp, const int* __restrict__ gptr,
               float* __restrict__ gpart) {
    __shared__ float red[16][128];   // 8KB
    int g = blockIdx.x / SPLIT, p = blockIdx.x % SPLIT;
    int e0 = rp[gptr[g]], e1 = rp[gptr[g + 1]];
    int len = e1 - e0;
    int blo = e0 + (int)((long long)len * p / SPLIT);
    int bhi = e0 + (int)((long long)len * (p + 1) / SPLIT);
    int qw = threadIdx.x >> 4;       // 16 quarter-waves
    int l = threadIdx.x & 15;        // dim-octet (8 dims)
    float a0 = 0.f, a1 = 0.f, a2 = 0.f, a3 = 0.f,
          a4 = 0.f, a5 = 0.f, a6 = 0.f, a7 = 0.f;

    for (int t0 = blo + qw * 16; t0 < bhi; t0 += 256) {
        int j = t0 + l;
        long long epk = (j < bhi) ? __builtin_nontemporal_load(ep + j) : 0ll;
        int cnt = min(16, bhi - t0);
#pragma unroll 8
        for (int t = 0; t < cnt; t++) {
            long long ebc = __shfl(epk, t, 16);
            int s = (int)(ebc & 0xffffffffll);
            float w = __uint_as_float((unsigned)((unsigned long long)ebc >> 32));
            uint2 u = S1f8[(size_t)s * 16 + l];
            f32x2 p0 = __builtin_amdgcn_cvt_pk_f32_fp8((int)u.x, false);
            f32x2 p1 = __builtin_amdgcn_cvt_pk_f32_fp8((int)u.x, true);
            f32x2 p2 = __builtin_amdgcn_cvt_pk_f32_fp8((int)u.y, false);
            f32x2 p3 = __builtin_amdgcn_cvt_pk_f32_fp8((int)u.y, true);
            a0 = fmaf(w, p0[0], a0);
            a1 = fmaf(w, p0[1], a1);
            a2 = fmaf(w, p1[0], a2);
            a3 = fmaf(w, p1[1], a3);
            a4 = fmaf(w, p2[0], a4);
            a5 = fmaf(w, p2[1], a5);
            a6 = fmaf(w, p3[0], a6);
            a7 = fmaf(w, p3[1], a7);
        }
    }
    float* rr = &red[qw][l * 8];
    rr[0] = a0; rr[1] = a1; rr[2] = a2; rr[3] = a3;
    rr[4] = a4; rr[5] = a5; rr[6] = a6; rr[7] = a7;
    __syncthreads();
    int d = threadIdx.x;
    if (d < 128) {
        float s = 0.f;
#pragma unroll
        for (int q = 0; q < 16; q++) s += red[q][d];
        gpart[(size_t)(g * SPLIT + p) * 128 + d] = s;
    }
}

// ======================= graph bounds + FF ==================================

__global__ __launch_bounds__(256)
void bounds_kernel(const int* __restrict__ gid, int* __restrict__ ptr, int n) {
    int i = blockIdx.x * 256 + threadIdx.x;
    if (i >= n) return;
    int b = gid[i];
    int a = (i == 0) ? -1 : gid[i - 1];
    for (int g = a + 1; g <= b; g++) ptr[g] = i;
    if (i == n - 1) {
        for (int g = b + 1; g <= G; g++) ptr[g] = n;
    }
}

// pooled[g] = (sum_p gpart) @ W2 / cnt + b2, then 3-layer FF + shortcut + sigmoid
__global__ __launch_bounds__(128)
void ff_kernel(const float* __restrict__ gpart, const int* __restrict__ gptr,
               const float* __restrict__ W2, const float* __restrict__ b2,
               const float* __restrict__ W1, const float* __restrict__ b1,
               const float* __restrict__ Wf2, const float* __restrict__ bf2,
               const float* __restrict__ W3, const float* __restrict__ b3,
               const float* __restrict__ Wsc, const float* __restrict__ bsc,
               float* __restrict__ ffout) {
    __shared__ float gs[D], hx[D], za[D], zb[D];
    int g = blockIdx.x, d = threadIdx.x;
    float s = 0.f;
#pragma unroll
    for (int p = 0; p < SPLIT; p++)
        s += gpart[(size_t)(g * SPLIT + p) * 128 + d];
    gs[d] = s;
    __syncthreads();
    int cnt = gptr[g + 1] - gptr[g];
    s = 0.f;
    for (int k = 0; k < D; k++) s = fmaf(gs[k], W2[k * D + d], s);
    hx[d] = (cnt > 0) ? (s / (float)cnt + b2[d]) : 0.f;
    __syncthreads();
    s = b1[d];
    for (int k = 0; k < D; k++) s = fmaf(hx[k], W1[k * D + d], s);
    za[d] = fmaxf(s, 0.f);
    __syncthreads();
    s = bf2[d];
    for (int k = 0; k < D; k++) s = fmaf(za[k], Wf2[k * D + d], s);
    zb[d] = fmaxf(s, 0.f);
    __syncthreads();
    s = b3[d];
    for (int k = 0; k < D; k++) s = fmaf(zb[k], W3[k * D + d], s);
    float z3 = fmaxf(s, 0.f);
    float sc = bsc[d];
    for (int k = 0; k < D; k++) sc = fmaf(hx[k], Wsc[k * D + d], sc);
    float v = z3 + sc;
    ffout[g * D + d] = 1.f / (1.f + expf(-v));
}

__global__ __launch_bounds__(256)
void scatter_kernel(const float* __restrict__ ffout, const int* __restrict__ gid,
                    float* __restrict__ out, int n) {
    unsigned idx = blockIdx.x * 256u + threadIdx.x;
    unsigned node = idx >> 5;
    if (node >= (unsigned)n) return;
    int d0 = (idx & 31) * 4;
    int g = gid[node];
    *(float4*)(out + (size_t)node * D + d0) = *(const float4*)(ffout + g * D + d0);
}

extern "C" void kernel_launch(void* const* d_in, const int* in_sizes, int n_in,
                              void* d_out, int out_size, void* d_ws, size_t ws_size,
                              hipStream_t stream) {
    const float* feat = (const float*)d_in[0];
    const float* ew   = (const float*)d_in[1];
    const float* W1   = (const float*)d_in[2];
    const float* b1   = (const float*)d_in[3];
    const float* W2   = (const float*)d_in[4];
    const float* b2   = (const float*)d_in[5];
    const float* ffW1 = (const float*)d_in[6];
    const float* ffb1 = (const float*)d_in[7];
    const float* ffW2 = (const float*)d_in[8];
    const float* ffb2 = (const float*)d_in[9];
    const float* ffW3 = (const float*)d_in[10];
    const float* ffb3 = (const float*)d_in[11];
    const float* ffWs = (const float*)d_in[12];
    const float* ffbs = (const float*)d_in[13];
    const int* esrc = (const int*)d_in[14];
    const int* edst = (const int*)d_in[15];
    const int* gid  = (const int*)d_in[16];

    const int N = in_sizes[0] / D;
    const int E = in_sizes[1];
    float* out = (float*)d_out;

    const int rpb = (N + NB - 1) / NB;        // 196 (<=256 required by bucket_sort)
    const int chunk = (E + NBLK - 1) / NBLK;  // edges per scatter block

    // workspace layout
    char* ws = (char*)d_ws;
    int2* ep = (int2*)ws;                                   // E int2 = 12.8MB
    unsigned char* A = (unsigned char*)(ep + E);            // N*128 fp8 = 12.8MB
    int2* tmp_p = (int2*)(A + (size_t)N * D);               // E int2 = 12.8MB (packed)
    float* ffo = (float*)(tmp_p + E);                       // G*D
    int* gptr = (int*)(ffo + G * D);                        // G+1 (+pad)
    int* row_ptr = gptr + G + 2;                            // N+1
    int* bbase = row_ptr + N + 1;                           // NB+1
    int* bsum = bbase + NB + 1;                             // NB
    int* counts = bsum + NB;                                // NB*NBLK = 1MB
    short* WT1 = (short*)(counts + NB * NBLK);              // 128*128 bf16
    float* gpart = (float*)(WT1 + 128 * 128);               // G*SPLIT*128 = 1MB

    unsigned char* S1 = (unsigned char*)d_out;  // fp8 layer-1 act (front 12.8MB)

    const dim3 blk(256);
    const int nGrid = (N + 255) / 256;
    const int ngroups = (N + 15) / 16;
    const int gemmGrid = (ngroups + 7) / 8;

    // ---- weight transpose+bf16 (tiny)
    prep_wt<<<64, blk, 0, stream>>>(W1, WT1);

    // ---- CSR build (atomic-free radix partition; LDS atomics only)
    radix_count<<<NBLK, blk, 0, stream>>>(edst, counts, E, rpb, chunk);
    radix_scan_rel<<<NB, blk, 0, stream>>>(counts, bsum);
    radix_base<<<1, NB, 0, stream>>>(bsum, bbase, row_ptr, E, N);
    radix_scatter<<<NBLK, blk, 0, stream>>>(esrc, edst, ew, counts, bbase,
                                            tmp_p, E, rpb, chunk);
    bucket_sort<<<NB, blk, 0, stream>>>(tmp_p, bbase, ep, row_ptr, N, rpb);

    // ---- graph boundaries from sorted gid
    bounds_kernel<<<nGrid, blk, 0, stream>>>(gid, gptr, N);

    // ---- pipeline
    // A1 = fp8(feat @ W1)
    gemm_mfma_f32in<<<gemmGrid, blk, 0, stream>>>(feat, WT1, A, N);
    // S1 = fp8(relu(spmm(A1) + b1))
    spmm_csr_fused<<<(N + 15) / 16, blk, 0, stream>>>((const uint2*)A, (const long long*)ep,
                                                      row_ptr, b1, (uint2*)S1, N);
    // gpart = per-graph partial sums of w_e * S1[src_e]
    graph_sum<<<G * SPLIT, blk, 0, stream>>>((const uint2*)S1, (const long long*)ep,
                                             row_ptr, gptr, gpart);
    // pooled = (sum gpart) @ W2 / cnt + b2; FF MLP + shortcut + sigmoid
    ff_kernel<<<G, 128, 0, stream>>>(gpart, gptr, W2, b2,
                                     ffW1, ffb1, ffW2, ffb2,
                                     ffW3, ffb3, ffWs, ffbs, ffo);
    // out[n] = ffo[graph_id[n]]
    scatter_kernel<<<(int)(((size_t)N * 32 + 255) / 256), blk, 0, stream>>>(ffo, gid, out, N);
}

// Round 15
// 183.410 us; speedup vs baseline: 1.8597x; 1.0741x over previous
//
#include <hip/hip_runtime.h>
#include <math.h>

// ---------------------------------------------------------------------------
// Encoder: GCN(2 layers) + per-graph mean pool + FF MLP on pooled rows + sigmoid
// N=100000 nodes, E=1600000 edges, D=128, G=256 graphs (graph_id sorted)
// Round 15: calibrated gather batching (batch-4 x uint2, named registers).
//   r14 counters: spmm 48us, VALU 26% (12.5us), HBM 15.5us, L2 6us => half
//   stall, ~1 outstanding gather/wave (VGPR 20; runtime-bound unroll doesn't
//   batch). r11's failure was batch-8 x uint4 (4x the bytes in flight at 2x
//   the traffic); now fp8 rows + batch-4 x uint2 = +8 VGPR only.
// ---------------------------------------------------------------------------

#define D 128
#define G 256
#define NB 512     // dst buckets (rows-per-bucket = ceil(N/NB) = 196 <= 256)
#define NBLK 512   // scatter blocks (each owns a contiguous edge chunk)
#define SPLIT 8    // partial-sum blocks per graph in graph_sum (deterministic)

typedef __attribute__((ext_vector_type(8))) short bf16x8;
typedef __attribute__((ext_vector_type(4))) float f32x4;
typedef __attribute__((ext_vector_type(2))) float f32x2;

__device__ __forceinline__ unsigned short f2bf(float f) {
    unsigned u = __float_as_uint(f);
    unsigned r = (u + 0x7fffu + ((u >> 16) & 1u)) >> 16;   // round-nearest-even
    return (unsigned short)r;
}

// pack 4 f32 -> 4 fp8 e4m3 bytes (byte i = value i)
__device__ __forceinline__ unsigned pack_fp8x4(float a, float b, float c, float d) {
    int v = __builtin_amdgcn_cvt_pk_fp8_f32(a, b, 0, false);   // bytes 0,1
    v = __builtin_amdgcn_cvt_pk_fp8_f32(c, d, v, true);        // bytes 2,3
    return (unsigned)v;
}

// fma 8 fp8 dims (one uint2) into 8 accumulators
#define FMA_FP8(u, w)                                                   \
    {                                                                   \
        f32x2 q0 = __builtin_amdgcn_cvt_pk_f32_fp8((int)(u).x, false);  \
        f32x2 q1 = __builtin_amdgcn_cvt_pk_f32_fp8((int)(u).x, true);   \
        f32x2 q2 = __builtin_amdgcn_cvt_pk_f32_fp8((int)(u).y, false);  \
        f32x2 q3 = __builtin_amdgcn_cvt_pk_f32_fp8((int)(u).y, true);   \
        a0 = fmaf((w), q0[0], a0);  a1 = fmaf((w), q0[1], a1);          \
        a2 = fmaf((w), q1[0], a2);  a3 = fmaf((w), q1[1], a3);          \
        a4 = fmaf((w), q2[0], a4);  a5 = fmaf((w), q2[1], a5);          \
        a6 = fmaf((w), q3[0], a6);  a7 = fmaf((w), q3[1], a7);          \
    }

// ---- one-time: WT1[c][k] = bf16(W1[k][c])  (128x128)
__global__ __launch_bounds__(256)
void prep_wt(const float* __restrict__ W, short* __restrict__ WT) {
    int idx = blockIdx.x * 256 + threadIdx.x;
    if (idx >= 128 * 128) return;
    int k = idx >> 7, c = idx & 127;
    WT[c * 128 + k] = (short)f2bf(W[k * 128 + c]);
}

// ---- MFMA GEMM (fp32 input): Y_fp8 = X_f32 @ W   (WT = W^T bf16)
__global__ __launch_bounds__(256, 2)
void gemm_mfma_f32in(const float* __restrict__ X, const short* __restrict__ WT,
                     unsigned char* __restrict__ Y, int nrows) {
    const int lane = threadIdx.x & 63;
    const int lr = lane & 15;
    const int lq = lane >> 4;
    const int wid = blockIdx.x * 4 + (threadIdx.x >> 6);
    const int nwaves = gridDim.x * 4;
    const int ngroups = (nrows + 15) >> 4;

    bf16x8 wf[8][4];
#pragma unroll
    for (int mt = 0; mt < 8; mt++)
#pragma unroll
        for (int ks = 0; ks < 4; ks++)
            wf[mt][ks] = *(const bf16x8*)(WT + (mt * 16 + lr) * 128 + ks * 32 + lq * 8);

    for (int g = wid; g < ngroups; g += nwaves) {
        int node = g * 16 + lr;
        int nrow = min(node, nrows - 1);
        const float* xp = X + (size_t)nrow * D + lq * 8;
        f32x4 acc[8];
#pragma unroll
        for (int mt = 0; mt < 8; mt++) acc[mt] = (f32x4){0.f, 0.f, 0.f, 0.f};

#pragma unroll
        for (int ks = 0; ks < 4; ks++) {
            float4 v0 = *(const float4*)(xp + ks * 32);
            float4 v1 = *(const float4*)(xp + ks * 32 + 4);
            bf16x8 xb;
            xb[0] = (short)f2bf(v0.x);
            xb[1] = (short)f2bf(v0.y);
            xb[2] = (short)f2bf(v0.z);
            xb[3] = (short)f2bf(v0.w);
            xb[4] = (short)f2bf(v1.x);
            xb[5] = (short)f2bf(v1.y);
            xb[6] = (short)f2bf(v1.z);
            xb[7] = (short)f2bf(v1.w);
#pragma unroll
            for (int mt = 0; mt < 8; mt++)
                acc[mt] = __builtin_amdgcn_mfma_f32_16x16x32_bf16(wf[mt][ks], xb, acc[mt], 0, 0, 0);
        }

        if (node < nrows) {
            unsigned char* yp = Y + (size_t)node * D + lq * 4;
#pragma unroll
            for (int mt = 0; mt < 8; mt++) {
                unsigned o = pack_fp8x4(acc[mt][0], acc[mt][1], acc[mt][2], acc[mt][3]);
                *(unsigned*)(yp + mt * 16) = o;
            }
        }
    }
}

// ============== CSR build: atomic-free radix partition + bucket sort ========

__global__ __launch_bounds__(256)
void radix_count(const int* __restrict__ dst, int* __restrict__ counts,
                 int ne, int rpb, int chunk) {
    __shared__ int h[NB];
    for (int i = threadIdx.x; i < NB; i += 256) h[i] = 0;
    __syncthreads();
    int b = blockIdx.x;
    int lo = b * chunk, hi = min(lo + chunk, ne);
    for (int e = lo + threadIdx.x; e < hi; e += 256)
        atomicAdd(&h[dst[e] / rpb], 1);
    __syncthreads();
    for (int k = threadIdx.x; k < NB; k += 256)
        counts[k * NBLK + b] = h[k];
}

__global__ __launch_bounds__(256)
void radix_scan_rel(int* __restrict__ counts, int* __restrict__ bsum) {
    __shared__ int s[256];
    int k = blockIdx.x, t = threadIdx.x;
    int base = k * NBLK + t * 2;
    int v0 = counts[base], v1 = counts[base + 1];
    int sum = v0 + v1;
    s[t] = sum;
    __syncthreads();
    for (int off = 1; off < 256; off <<= 1) {
        int x = (t >= off) ? s[t - off] : 0;
        __syncthreads();
        s[t] += x;
        __syncthreads();
    }
    int ex = s[t] - sum;
    counts[base] = ex;
    counts[base + 1] = ex + v0;
    if (t == 255) bsum[k] = s[255];
}

__global__ __launch_bounds__(NB)
void radix_base(const int* __restrict__ bsum, int* __restrict__ bbase,
                int* __restrict__ row_ptr, int ne, int n) {
    __shared__ int s[NB];
    int t = threadIdx.x;
    int v = bsum[t];
    s[t] = v;
    __syncthreads();
    for (int off = 1; off < NB; off <<= 1) {
        int x = (t >= off) ? s[t - off] : 0;
        __syncthreads();
        s[t] += x;
        __syncthreads();
    }
    bbase[t + 1] = s[t];
    if (t == 0) { bbase[0] = 0; row_ptr[n] = ne; }
}

// ONE 8B record per edge: (src | lr<<20, w_fp32). src<2^20, lr<256.
__global__ __launch_bounds__(256)
void radix_scatter(const int* __restrict__ src, const int* __restrict__ dst,
                   const float* __restrict__ ew,
                   const int* __restrict__ counts, const int* __restrict__ bbase,
                   int2* __restrict__ tmp_p, int ne, int rpb, int chunk) {
    __shared__ int cur[NB];
    int b = blockIdx.x;
    for (int k = threadIdx.x; k < NB; k += 256)
        cur[k] = bbase[k] + counts[k * NBLK + b];
    __syncthreads();
    int lo = b * chunk, hi = min(lo + chunk, ne);
    for (int e = lo + threadIdx.x; e < hi; e += 256) {
        int d = dst[e];
        int k = d / rpb;
        int pos = atomicAdd(&cur[k], 1);          // LDS atomic
        tmp_p[pos] = make_int2(src[e] | ((d - k * rpb) << 20), __float_as_int(ew[e]));
    }
}

__global__ __launch_bounds__(256)
void bucket_sort(const int2* __restrict__ tmp_p,
                 const int* __restrict__ bbase, int2* __restrict__ ep,
                 int* __restrict__ row_ptr, int n, int rpb) {
    __shared__ int cnt[256], scn[256], cur[256];
    int b = blockIdx.x, t = threadIdx.x;
    int e0 = bbase[b], e1 = bbase[b + 1];
    int r0 = b * rpb;
    cnt[t] = 0;
    __syncthreads();
    for (int i = e0 + t; i < e1; i += 256)
        atomicAdd(&cnt[(unsigned)tmp_p[i].x >> 20], 1);
    __syncthreads();
    int v = cnt[t];
    scn[t] = v;
    __syncthreads();
    for (int off = 1; off < 256; off <<= 1) {
        int x = (t >= off) ? scn[t - off] : 0;
        __syncthreads();
        scn[t] += x;
        __syncthreads();
    }
    int ex = scn[t] - v;
    cur[t] = ex;
    int grow = r0 + t;
    if (t < rpb && grow < n) row_ptr[grow] = e0 + ex;
    __syncthreads();
    for (int i = e0 + t; i < e1; i += 256) {
        int2 rec = tmp_p[i];
        int r = (unsigned)rec.x >> 20;
        int pos = e0 + atomicAdd(&cur[r], 1);     // LDS atomic
        ep[pos] = make_int2(rec.x & 0xFFFFF, rec.y);
    }
}

// ---- Layer-1 SpMM: quarter-wave per row (16 lanes x uint2 = 128B fp8 row);
// batch-4 named-register gathers; fused relu(.+b1) -> fp8 out.
__global__ __launch_bounds__(256)
void spmm_csr_fused(const uint2* __restrict__ Xf8, const long long* __restrict__ ep,
                    const int* __restrict__ rp, const float* __restrict__ bias,
                    uint2* __restrict__ outv, int nrows) {
    int row = blockIdx.x * 16 + (threadIdx.x >> 4);
    if (row >= nrows) return;
    int l = threadIdx.x & 15;             // dim-octet index (8 dims)
    int beg = rp[row], end = rp[row + 1];
    float a0 = 0.f, a1 = 0.f, a2 = 0.f, a3 = 0.f,
          a4 = 0.f, a5 = 0.f, a6 = 0.f, a7 = 0.f;

    for (int t0 = beg; t0 < end; t0 += 16) {
        int j = t0 + l;
        long long epk = (j < end) ? __builtin_nontemporal_load(ep + j) : 0ll;
        int cnt = min(16, end - t0);
        int t = 0;
        for (; t + 4 <= cnt; t += 4) {
            long long e0 = __shfl(epk, t, 16);
            long long e1 = __shfl(epk, t + 1, 16);
            long long e2 = __shfl(epk, t + 2, 16);
            long long e3 = __shfl(epk, t + 3, 16);
            // 4 independent gathers issued back-to-back
            uint2 u0 = Xf8[(size_t)(int)e0 * 16 + l];
            uint2 u1 = Xf8[(size_t)(int)e1 * 16 + l];
            uint2 u2 = Xf8[(size_t)(int)e2 * 16 + l];
            uint2 u3 = Xf8[(size_t)(int)e3 * 16 + l];
            float w0 = __uint_as_float((unsigned)((unsigned long long)e0 >> 32));
            float w1 = __uint_as_float((unsigned)((unsigned long long)e1 >> 32));
            float w2 = __uint_as_float((unsigned)((unsigned long long)e2 >> 32));
            float w3 = __uint_as_float((unsigned)((unsigned long long)e3 >> 32));
            FMA_FP8(u0, w0)
            FMA_FP8(u1, w1)
            FMA_FP8(u2, w2)
            FMA_FP8(u3, w3)
        }
        for (; t < cnt; t++) {
            long long eb = __shfl(epk, t, 16);
            float w = __uint_as_float((unsigned)((unsigned long long)eb >> 32));
            uint2 u = Xf8[(size_t)(int)eb * 16 + l];
            FMA_FP8(u, w)
        }
    }
    const float4 b0 = *(const float4*)(bias + l * 8);
    const float4 b1v = *(const float4*)(bias + l * 8 + 4);
    a0 = fmaxf(a0 + b0.x, 0.f);  a1 = fmaxf(a1 + b0.y, 0.f);
    a2 = fmaxf(a2 + b0.z, 0.f);  a3 = fmaxf(a3 + b0.w, 0.f);
    a4 = fmaxf(a4 + b1v.x, 0.f); a5 = fmaxf(a5 + b1v.y, 0.f);
    a6 = fmaxf(a6 + b1v.z, 0.f); a7 = fmaxf(a7 + b1v.w, 0.f);
    uint2 p;
    p.x = pack_fp8x4(a0, a1, a2, a3);
    p.y = pack_fp8x4(a4, a5, a6, a7);
    outv[(size_t)row * 16 + l] = p;   // fp8 row = 128B = 16 uint2
}

// ---- graph_sum: gpart[g*SPLIT+p][d] = Sum_{edge chunk} w_e * S1[src_e][d]
__global__ __launch_bounds__(256)
void graph_sum(const uint2* __restrict__ S1f8, const long long* __restrict__ ep,
               const int* __restrict__ rp, const int* __restrict__ gptr,
               float* __restrict__ gpart) {
    __shared__ float red[16][128];   // 8KB
    int g = blockIdx.x / SPLIT, p = blockIdx.x % SPLIT;
    int e0s = rp[gptr[g]], e1s = rp[gptr[g + 1]];
    int len = e1s - e0s;
    int blo = e0s + (int)((long long)len * p / SPLIT);
    int bhi = e0s + (int)((long long)len * (p + 1) / SPLIT);
    int qw = threadIdx.x >> 4;       // 16 quarter-waves
    int l = threadIdx.x & 15;        // dim-octet (8 dims)
    float a0 = 0.f, a1 = 0.f, a2 = 0.f, a3 = 0.f,
          a4 = 0.f, a5 = 0.f, a6 = 0.f, a7 = 0.f;

    for (int t0 = blo + qw * 16; t0 < bhi; t0 += 256) {
        int j = t0 + l;
        long long epk = (j < bhi) ? __builtin_nontemporal_load(ep + j) : 0ll;
        int cnt = min(16, bhi - t0);
        int t = 0;
        for (; t + 4 <= cnt; t += 4) {
            long long e0 = __shfl(epk, t, 16);
            long long e1 = __shfl(epk, t + 1, 16);
            long long e2 = __shfl(epk, t + 2, 16);
            long long e3 = __shfl(epk, t + 3, 16);
            uint2 u0 = S1f8[(size_t)(int)e0 * 16 + l];
            uint2 u1 = S1f8[(size_t)(int)e1 * 16 + l];
            uint2 u2 = S1f8[(size_t)(int)e2 * 16 + l];
            uint2 u3 = S1f8[(size_t)(int)e3 * 16 + l];
            float w0 = __uint_as_float((unsigned)((unsigned long long)e0 >> 32));
            float w1 = __uint_as_float((unsigned)((unsigned long long)e1 >> 32));
            float w2 = __uint_as_float((unsigned)((unsigned long long)e2 >> 32));
            float w3 = __uint_as_float((unsigned)((unsigned long long)e3 >> 32));
            FMA_FP8(u0, w0)
            FMA_FP8(u1, w1)
            FMA_FP8(u2, w2)
            FMA_FP8(u3, w3)
        }
        for (; t < cnt; t++) {
            long long eb = __shfl(epk, t, 16);
            float w = __uint_as_float((unsigned)((unsigned long long)eb >> 32));
            uint2 u = S1f8[(size_t)(int)eb * 16 + l];
            FMA_FP8(u, w)
        }
    }
    float* rr = &red[qw][l * 8];
    rr[0] = a0; rr[1] = a1; rr[2] = a2; rr[3] = a3;
    rr[4] = a4; rr[5] = a5; rr[6] = a6; rr[7] = a7;
    __syncthreads();
    int d = threadIdx.x;
    if (d < 128) {
        float s = 0.f;
#pragma unroll
        for (int q = 0; q < 16; q++) s += red[q][d];
        gpart[(size_t)(g * SPLIT + p) * 128 + d] = s;
    }
}

// ======================= graph bounds + FF ==================================

__global__ __launch_bounds__(256)
void bounds_kernel(const int* __restrict__ gid, int* __restrict__ ptr, int n) {
    int i = blockIdx.x * 256 + threadIdx.x;
    if (i >= n) return;
    int b = gid[i];
    int a = (i == 0) ? -1 : gid[i - 1];
    for (int g = a + 1; g <= b; g++) ptr[g] = i;
    if (i == n - 1) {
        for (int g = b + 1; g <= G; g++) ptr[g] = n;
    }
}

// pooled[g] = (sum_p gpart) @ W2 / cnt + b2, then 3-layer FF + shortcut + sigmoid
__global__ __launch_bounds__(128)
void ff_kernel(const float* __restrict__ gpart, const int* __restrict__ gptr,
               const float* __restrict__ W2, const float* __restrict__ b2,
               const float* __restrict__ W1, const float* __restrict__ b1,
               const float* __restrict__ Wf2, const float* __restrict__ bf2,
               const float* __restrict__ W3, const float* __restrict__ b3,
               const float* __restrict__ Wsc, const float* __restrict__ bsc,
               float* __restrict__ ffout) {
    __shared__ float gs[D], hx[D], za[D], zb[D];
    int g = blockIdx.x, d = threadIdx.x;
    float s = 0.f;
#pragma unroll
    for (int p = 0; p < SPLIT; p++)
        s += gpart[(size_t)(g * SPLIT + p) * 128 + d];
    gs[d] = s;
    __syncthreads();
    int cnt = gptr[g + 1] - gptr[g];
    s = 0.f;
    for (int k = 0; k < D; k++) s = fmaf(gs[k], W2[k * D + d], s);
    hx[d] = (cnt > 0) ? (s / (float)cnt + b2[d]) : 0.f;
    __syncthreads();
    s = b1[d];
    for (int k = 0; k < D; k++) s = fmaf(hx[k], W1[k * D + d], s);
    za[d] = fmaxf(s, 0.f);
    __syncthreads();
    s = bf2[d];
    for (int k = 0; k < D; k++) s = fmaf(za[k], Wf2[k * D + d], s);
    zb[d] = fmaxf(s, 0.f);
    __syncthreads();
    s = b3[d];
    for (int k = 0; k < D; k++) s = fmaf(zb[k], W3[k * D + d], s);
    float z3 = fmaxf(s, 0.f);
    float sc = bsc[d];
    for (int k = 0; k < D; k++) sc = fmaf(hx[k], Wsc[k * D + d], sc);
    float v = z3 + sc;
    ffout[g * D + d] = 1.f / (1.f + expf(-v));
}

__global__ __launch_bounds__(256)
void scatter_kernel(const float* __restrict__ ffout, const int* __restrict__ gid,
                    float* __restrict__ out, int n) {
    unsigned idx = blockIdx.x * 256u + threadIdx.x;
    unsigned node = idx >> 5;
    if (node >= (unsigned)n) return;
    int d0 = (idx & 31) * 4;
    int g = gid[node];
    *(float4*)(out + (size_t)node * D + d0) = *(const float4*)(ffout + g * D + d0);
}

extern "C" void kernel_launch(void* const* d_in, const int* in_sizes, int n_in,
                              void* d_out, int out_size, void* d_ws, size_t ws_size,
                              hipStream_t stream) {
    const float* feat = (const float*)d_in[0];
    const float* ew   = (const float*)d_in[1];
    const float* W1   = (const float*)d_in[2];
    const float* b1   = (const float*)d_in[3];
    const float* W2   = (const float*)d_in[4];
    const float* b2   = (const float*)d_in[5];
    const float* ffW1 = (const float*)d_in[6];
    const float* ffb1 = (const float*)d_in[7];
    const float* ffW2 = (const float*)d_in[8];
    const float* ffb2 = (const float*)d_in[9];
    const float* ffW3 = (const float*)d_in[10];
    const float* ffb3 = (const float*)d_in[11];
    const float* ffWs = (const float*)d_in[12];
    const float* ffbs = (const float*)d_in[13];
    const int* esrc = (const int*)d_in[14];
    const int* edst = (const int*)d_in[15];
    const int* gid  = (const int*)d_in[16];

    const int N = in_sizes[0] / D;
    const int E = in_sizes[1];
    float* out = (float*)d_out;

    const int rpb = (N + NB - 1) / NB;        // 196 (<=256 required by bucket_sort)
    const int chunk = (E + NBLK - 1) / NBLK;  // edges per scatter block

    // workspace layout
    char* ws = (char*)d_ws;
    int2* ep = (int2*)ws;                                   // E int2 = 12.8MB
    unsigned char* A = (unsigned char*)(ep + E);            // N*128 fp8 = 12.8MB
    int2* tmp_p = (int2*)(A + (size_t)N * D);               // E int2 = 12.8MB (packed)
    float* ffo = (float*)(tmp_p + E);                       // G*D
    int* gptr = (int*)(ffo + G * D);                        // G+1 (+pad)
    int* row_ptr = gptr + G + 2;                            // N+1
    int* bbase = row_ptr + N + 1;                           // NB+1
    int* bsum = bbase + NB + 1;                             // NB
    int* counts = bsum + NB;                                // NB*NBLK = 1MB
    short* WT1 = (short*)(counts + NB * NBLK);              // 128*128 bf16
    float* gpart = (float*)(WT1 + 128 * 128);               // G*SPLIT*128 = 1MB

    unsigned char* S1 = (unsigned char*)d_out;  // fp8 layer-1 act (front 12.8MB)

    const dim3 blk(256);
    const int nGrid = (N + 255) / 256;
    const int ngroups = (N + 15) / 16;
    const int gemmGrid = (ngroups + 7) / 8;

    // ---- weight transpose+bf16 (tiny)
    prep_wt<<<64, blk, 0, stream>>>(W1, WT1);

    // ---- CSR build (atomic-free radix partition; LDS atomics only)
    radix_count<<<NBLK, blk, 0, stream>>>(edst, counts, E, rpb, chunk);
    radix_scan_rel<<<NB, blk, 0, stream>>>(counts, bsum);
    radix_base<<<1, NB, 0, stream>>>(bsum, bbase, row_ptr, E, N);
    radix_scatter<<<NBLK, blk, 0, stream>>>(esrc, edst, ew, counts, bbase,
                                            tmp_p, E, rpb, chunk);
    bucket_sort<<<NB, blk, 0, stream>>>(tmp_p, bbase, ep, row_ptr, N, rpb);

    // ---- graph boundaries from sorted gid
    bounds_kernel<<<nGrid, blk, 0, stream>>>(gid, gptr, N);

    // ---- pipeline
    // A1 = fp8(feat @ W1)
    gemm_mfma_f32in<<<gemmGrid, blk, 0, stream>>>(feat, WT1, A, N);
    // S1 = fp8(relu(spmm(A1) + b1))
    spmm_csr_fused<<<(N + 15) / 16, blk, 0, stream>>>((const uint2*)A, (const long long*)ep,
                                                      row_ptr, b1, (uint2*)S1, N);
    // gpart = per-graph partial sums of w_e * S1[src_e]
    graph_sum<<<G * SPLIT, blk, 0, stream>>>((const uint2*)S1, (const long long*)ep,
                                             row_ptr, gptr, gpart);
    // pooled = (sum gpart) @ W2 / cnt + b2; FF MLP + shortcut + sigmoid
    ff_kernel<<<G, 128, 0, stream>>>(gpart, gptr, W2, b2,
                                     ffW1, ffb1, ffW2, ffb2,
                                     ffW3, ffb3, ffWs, ffbs, ffo);
    // out[n] = ffo[graph_id[n]]
    scatter_kernel<<<(int)(((size_t)N * 32 + 255) / 256), blk, 0, stream>>>(ffo, gid, out, N);
}

// Round 16
// 181.887 us; speedup vs baseline: 1.8752x; 1.0084x over previous
//
#include <hip/hip_runtime.h>
#include <math.h>

// ---------------------------------------------------------------------------
// Encoder: GCN(2 layers) + per-graph mean pool + FF MLP on pooled rows + sigmoid
// N=100000 nodes, E=1600000 edges, D=128, G=256 graphs (graph_id sorted)
// Round 16:
//  - radix_count/radix_scatter: 1024-thread blocks (was 256). Grid=512 blocks
//    = 2/CU; 256thr => only 8 waves/CU (25%) to hide the scattered-store /
//    cross-XCD line-sharing latency (VALUBusy was 2%). Now 32 waves/CU.
//  - spmm/graph_sum: full 16-edge tiles as two batch-8 named-register gather
//    groups (fp8 rows => 64B/lane in flight; r11's failure was 128B/lane at
//    2x traffic). Remainder keeps batch-4/1 path.
// ---------------------------------------------------------------------------

#define D 128
#define G 256
#define NB 512     // dst buckets (rows-per-bucket = ceil(N/NB) = 196 <= 256)
#define NBLK 512   // scatter blocks (each owns a contiguous edge chunk)
#define SPLIT 8    // partial-sum blocks per graph in graph_sum (deterministic)

typedef __attribute__((ext_vector_type(8))) short bf16x8;
typedef __attribute__((ext_vector_type(4))) float f32x4;
typedef __attribute__((ext_vector_type(2))) float f32x2;

__device__ __forceinline__ unsigned short f2bf(float f) {
    unsigned u = __float_as_uint(f);
    unsigned r = (u + 0x7fffu + ((u >> 16) & 1u)) >> 16;   // round-nearest-even
    return (unsigned short)r;
}

// pack 4 f32 -> 4 fp8 e4m3 bytes (byte i = value i)
__device__ __forceinline__ unsigned pack_fp8x4(float a, float b, float c, float d) {
    int v = __builtin_amdgcn_cvt_pk_fp8_f32(a, b, 0, false);   // bytes 0,1
    v = __builtin_amdgcn_cvt_pk_fp8_f32(c, d, v, true);        // bytes 2,3
    return (unsigned)v;
}

// fma 8 fp8 dims (one uint2) into 8 accumulators
#define FMA_FP8(u, w)                                                   \
    {                                                                   \
        f32x2 q0 = __builtin_amdgcn_cvt_pk_f32_fp8((int)(u).x, false);  \
        f32x2 q1 = __builtin_amdgcn_cvt_pk_f32_fp8((int)(u).x, true);   \
        f32x2 q2 = __builtin_amdgcn_cvt_pk_f32_fp8((int)(u).y, false);  \
        f32x2 q3 = __builtin_amdgcn_cvt_pk_f32_fp8((int)(u).y, true);   \
        a0 = fmaf((w), q0[0], a0);  a1 = fmaf((w), q0[1], a1);          \
        a2 = fmaf((w), q1[0], a2);  a3 = fmaf((w), q1[1], a3);          \
        a4 = fmaf((w), q2[0], a4);  a5 = fmaf((w), q2[1], a5);          \
        a6 = fmaf((w), q3[0], a6);  a7 = fmaf((w), q3[1], a7);          \
    }

#define W_OF(e) __uint_as_float((unsigned)((unsigned long long)(e) >> 32))
#define S_OF(e) ((size_t)(int)(e))

// 8 independent gathers issued back-to-back, then 8 FMA groups
#define GF8(TBL, epk, B)                                                \
    {                                                                   \
        long long x0 = __shfl((epk), (B) + 0, 16);                      \
        long long x1 = __shfl((epk), (B) + 1, 16);                      \
        long long x2 = __shfl((epk), (B) + 2, 16);                      \
        long long x3 = __shfl((epk), (B) + 3, 16);                      \
        long long x4 = __shfl((epk), (B) + 4, 16);                      \
        long long x5 = __shfl((epk), (B) + 5, 16);                      \
        long long x6 = __shfl((epk), (B) + 6, 16);                      \
        long long x7 = __shfl((epk), (B) + 7, 16);                      \
        uint2 v0 = (TBL)[S_OF(x0) * 16 + l];                            \
        uint2 v1 = (TBL)[S_OF(x1) * 16 + l];                            \
        uint2 v2 = (TBL)[S_OF(x2) * 16 + l];                            \
        uint2 v3 = (TBL)[S_OF(x3) * 16 + l];                            \
        uint2 v4 = (TBL)[S_OF(x4) * 16 + l];                            \
        uint2 v5 = (TBL)[S_OF(x5) * 16 + l];                            \
        uint2 v6 = (TBL)[S_OF(x6) * 16 + l];                            \
        uint2 v7 = (TBL)[S_OF(x7) * 16 + l];                            \
        FMA_FP8(v0, W_OF(x0))                                           \
        FMA_FP8(v1, W_OF(x1))                                           \
        FMA_FP8(v2, W_OF(x2))                                           \
        FMA_FP8(v3, W_OF(x3))                                           \
        FMA_FP8(v4, W_OF(x4))                                           \
        FMA_FP8(v5, W_OF(x5))                                           \
        FMA_FP8(v6, W_OF(x6))                                           \
        FMA_FP8(v7, W_OF(x7))                                           \
    }

// ---- one-time: WT1[c][k] = bf16(W1[k][c])  (128x128)
__global__ __launch_bounds__(256)
void prep_wt(const float* __restrict__ W, short* __restrict__ WT) {
    int idx = blockIdx.x * 256 + threadIdx.x;
    if (idx >= 128 * 128) return;
    int k = idx >> 7, c = idx & 127;
    WT[c * 128 + k] = (short)f2bf(W[k * 128 + c]);
}

// ---- MFMA GEMM (fp32 input): Y_fp8 = X_f32 @ W   (WT = W^T bf16)
__global__ __launch_bounds__(256, 2)
void gemm_mfma_f32in(const float* __restrict__ X, const short* __restrict__ WT,
                     unsigned char* __restrict__ Y, int nrows) {
    const int lane = threadIdx.x & 63;
    const int lr = lane & 15;
    const int lq = lane >> 4;
    const int wid = blockIdx.x * 4 + (threadIdx.x >> 6);
    const int nwaves = gridDim.x * 4;
    const int ngroups = (nrows + 15) >> 4;

    bf16x8 wf[8][4];
#pragma unroll
    for (int mt = 0; mt < 8; mt++)
#pragma unroll
        for (int ks = 0; ks < 4; ks++)
            wf[mt][ks] = *(const bf16x8*)(WT + (mt * 16 + lr) * 128 + ks * 32 + lq * 8);

    for (int g = wid; g < ngroups; g += nwaves) {
        int node = g * 16 + lr;
        int nrow = min(node, nrows - 1);
        const float* xp = X + (size_t)nrow * D + lq * 8;
        f32x4 acc[8];
#pragma unroll
        for (int mt = 0; mt < 8; mt++) acc[mt] = (f32x4){0.f, 0.f, 0.f, 0.f};

#pragma unroll
        for (int ks = 0; ks < 4; ks++) {
            float4 v0 = *(const float4*)(xp + ks * 32);
            float4 v1 = *(const float4*)(xp + ks * 32 + 4);
            bf16x8 xb;
            xb[0] = (short)f2bf(v0.x);
            xb[1] = (short)f2bf(v0.y);
            xb[2] = (short)f2bf(v0.z);
            xb[3] = (short)f2bf(v0.w);
            xb[4] = (short)f2bf(v1.x);
            xb[5] = (short)f2bf(v1.y);
            xb[6] = (short)f2bf(v1.z);
            xb[7] = (short)f2bf(v1.w);
#pragma unroll
            for (int mt = 0; mt < 8; mt++)
                acc[mt] = __builtin_amdgcn_mfma_f32_16x16x32_bf16(wf[mt][ks], xb, acc[mt], 0, 0, 0);
        }

        if (node < nrows) {
            unsigned char* yp = Y + (size_t)node * D + lq * 4;
#pragma unroll
            for (int mt = 0; mt < 8; mt++) {
                unsigned o = pack_fp8x4(acc[mt][0], acc[mt][1], acc[mt][2], acc[mt][3]);
                *(unsigned*)(yp + mt * 16) = o;
            }
        }
    }
}

// ============== CSR build: atomic-free radix partition + bucket sort ========

__global__ __launch_bounds__(1024)
void radix_count(const int* __restrict__ dst, int* __restrict__ counts,
                 int ne, int rpb, int chunk) {
    __shared__ int h[NB];
    for (int i = threadIdx.x; i < NB; i += 1024) h[i] = 0;
    __syncthreads();
    int b = blockIdx.x;
    int lo = b * chunk, hi = min(lo + chunk, ne);
    for (int e = lo + threadIdx.x; e < hi; e += 1024)
        atomicAdd(&h[dst[e] / rpb], 1);
    __syncthreads();
    for (int k = threadIdx.x; k < NB; k += 1024)
        counts[k * NBLK + b] = h[k];
}

__global__ __launch_bounds__(256)
void radix_scan_rel(int* __restrict__ counts, int* __restrict__ bsum) {
    __shared__ int s[256];
    int k = blockIdx.x, t = threadIdx.x;
    int base = k * NBLK + t * 2;
    int v0 = counts[base], v1 = counts[base + 1];
    int sum = v0 + v1;
    s[t] = sum;
    __syncthreads();
    for (int off = 1; off < 256; off <<= 1) {
        int x = (t >= off) ? s[t - off] : 0;
        __syncthreads();
        s[t] += x;
        __syncthreads();
    }
    int ex = s[t] - sum;
    counts[base] = ex;
    counts[base + 1] = ex + v0;
    if (t == 255) bsum[k] = s[255];
}

__global__ __launch_bounds__(NB)
void radix_base(const int* __restrict__ bsum, int* __restrict__ bbase,
                int* __restrict__ row_ptr, int ne, int n) {
    __shared__ int s[NB];
    int t = threadIdx.x;
    int v = bsum[t];
    s[t] = v;
    __syncthreads();
    for (int off = 1; off < NB; off <<= 1) {
        int x = (t >= off) ? s[t - off] : 0;
        __syncthreads();
        s[t] += x;
        __syncthreads();
    }
    bbase[t + 1] = s[t];
    if (t == 0) { bbase[0] = 0; row_ptr[n] = ne; }
}

// ONE 8B record per edge: (src | lr<<20, w_fp32). src<2^20, lr<256.
__global__ __launch_bounds__(1024)
void radix_scatter(const int* __restrict__ src, const int* __restrict__ dst,
                   const float* __restrict__ ew,
                   const int* __restrict__ counts, const int* __restrict__ bbase,
                   int2* __restrict__ tmp_p, int ne, int rpb, int chunk) {
    __shared__ int cur[NB];
    int b = blockIdx.x;
    for (int k = threadIdx.x; k < NB; k += 1024)
        cur[k] = bbase[k] + counts[k * NBLK + b];
    __syncthreads();
    int lo = b * chunk, hi = min(lo + chunk, ne);
    for (int e = lo + threadIdx.x; e < hi; e += 1024) {
        int d = dst[e];
        int k = d / rpb;
        int pos = atomicAdd(&cur[k], 1);          // LDS atomic
        tmp_p[pos] = make_int2(src[e] | ((d - k * rpb) << 20), __float_as_int(ew[e]));
    }
}

__global__ __launch_bounds__(256)
void bucket_sort(const int2* __restrict__ tmp_p,
                 const int* __restrict__ bbase, int2* __restrict__ ep,
                 int* __restrict__ row_ptr, int n, int rpb) {
    __shared__ int cnt[256], scn[256], cur[256];
    int b = blockIdx.x, t = threadIdx.x;
    int e0 = bbase[b], e1 = bbase[b + 1];
    int r0 = b * rpb;
    cnt[t] = 0;
    __syncthreads();
    for (int i = e0 + t; i < e1; i += 256)
        atomicAdd(&cnt[(unsigned)tmp_p[i].x >> 20], 1);
    __syncthreads();
    int v = cnt[t];
    scn[t] = v;
    __syncthreads();
    for (int off = 1; off < 256; off <<= 1) {
        int x = (t >= off) ? scn[t - off] : 0;
        __syncthreads();
        scn[t] += x;
        __syncthreads();
    }
    int ex = scn[t] - v;
    cur[t] = ex;
    int grow = r0 + t;
    if (t < rpb && grow < n) row_ptr[grow] = e0 + ex;
    __syncthreads();
    for (int i = e0 + t; i < e1; i += 256) {
        int2 rec = tmp_p[i];
        int r = (unsigned)rec.x >> 20;
        int pos = e0 + atomicAdd(&cur[r], 1);     // LDS atomic
        ep[pos] = make_int2(rec.x & 0xFFFFF, rec.y);
    }
}

// ---- Layer-1 SpMM: quarter-wave per row (16 lanes x uint2 = 128B fp8 row);
// full tiles = 2x batch-8 named-register gathers; fused relu(.+b1) -> fp8 out.
__global__ __launch_bounds__(256)
void spmm_csr_fused(const uint2* __restrict__ Xf8, const long long* __restrict__ ep,
                    const int* __restrict__ rp, const float* __restrict__ bias,
                    uint2* __restrict__ outv, int nrows) {
    int row = blockIdx.x * 16 + (threadIdx.x >> 4);
    if (row >= nrows) return;
    int l = threadIdx.x & 15;             // dim-octet index (8 dims)
    int beg = rp[row], end = rp[row + 1];
    float a0 = 0.f, a1 = 0.f, a2 = 0.f, a3 = 0.f,
          a4 = 0.f, a5 = 0.f, a6 = 0.f, a7 = 0.f;

    for (int t0 = beg; t0 < end; t0 += 16) {
        int j = t0 + l;
        long long epk = (j < end) ? __builtin_nontemporal_load(ep + j) : 0ll;
        if (end - t0 >= 16) {
            GF8(Xf8, epk, 0)
            GF8(Xf8, epk, 8)
        } else {
            int cnt = end - t0;
            int t = 0;
            for (; t + 4 <= cnt; t += 4) {
                long long e0 = __shfl(epk, t, 16);
                long long e1 = __shfl(epk, t + 1, 16);
                long long e2 = __shfl(epk, t + 2, 16);
                long long e3 = __shfl(epk, t + 3, 16);
                uint2 u0 = Xf8[S_OF(e0) * 16 + l];
                uint2 u1 = Xf8[S_OF(e1) * 16 + l];
                uint2 u2 = Xf8[S_OF(e2) * 16 + l];
                uint2 u3 = Xf8[S_OF(e3) * 16 + l];
                FMA_FP8(u0, W_OF(e0))
                FMA_FP8(u1, W_OF(e1))
                FMA_FP8(u2, W_OF(e2))
                FMA_FP8(u3, W_OF(e3))
            }
            for (; t < cnt; t++) {
                long long eb = __shfl(epk, t, 16);
                uint2 u = Xf8[S_OF(eb) * 16 + l];
                FMA_FP8(u, W_OF(eb))
            }
        }
    }
    const float4 b0 = *(const float4*)(bias + l * 8);
    const float4 b1v = *(const float4*)(bias + l * 8 + 4);
    a0 = fmaxf(a0 + b0.x, 0.f);  a1 = fmaxf(a1 + b0.y, 0.f);
    a2 = fmaxf(a2 + b0.z, 0.f);  a3 = fmaxf(a3 + b0.w, 0.f);
    a4 = fmaxf(a4 + b1v.x, 0.f); a5 = fmaxf(a5 + b1v.y, 0.f);
    a6 = fmaxf(a6 + b1v.z, 0.f); a7 = fmaxf(a7 + b1v.w, 0.f);
    uint2 p;
    p.x = pack_fp8x4(a0, a1, a2, a3);
    p.y = pack_fp8x4(a4, a5, a6, a7);
    outv[(size_t)row * 16 + l] = p;   // fp8 row = 128B = 16 uint2
}

// ---- graph_sum: gpart[g*SPLIT+p][d] = Sum_{edge chunk} w_e * S1[src_e][d]
__global__ __launch_bounds__(256)
void graph_sum(const uint2* __restrict__ S1f8, const long long* __restrict__ ep,
               const int* __restrict__ rp, const int* __restrict__ gptr,
               float* __restrict__ gpart) {
    __shared__ float red[16][128];   // 8KB
    int g = blockIdx.x / SPLIT, p = blockIdx.x % SPLIT;
    int e0s = rp[gptr[g]], e1s = rp[gptr[g + 1]];
    int len = e1s - e0s;
    int blo = e0s + (int)((long long)len * p / SPLIT);
    int bhi = e0s + (int)((long long)len * (p + 1) / SPLIT);
    int qw = threadIdx.x >> 4;       // 16 quarter-waves
    int l = threadIdx.x & 15;        // dim-octet (8 dims)
    float a0 = 0.f, a1 = 0.f, a2 = 0.f, a3 = 0.f,
          a4 = 0.f, a5 = 0.f, a6 = 0.f, a7 = 0.f;

    for (int t0 = blo + qw * 16; t0 < bhi; t0 += 256) {
        int j = t0 + l;
        long long epk = (j < bhi) ? __builtin_nontemporal_load(ep + j) : 0ll;
        if (bhi - t0 >= 16) {
            GF8(S1f8, epk, 0)
            GF8(S1f8, epk, 8)
        } else {
            int cnt = bhi - t0;
            int t = 0;
            for (; t + 4 <= cnt; t += 4) {
                long long e0 = __shfl(epk, t, 16);
                long long e1 = __shfl(epk, t + 1, 16);
                long long e2 = __shfl(epk, t + 2, 16);
                long long e3 = __shfl(epk, t + 3, 16);
                uint2 u0 = S1f8[S_OF(e0) * 16 + l];
                uint2 u1 = S1f8[S_OF(e1) * 16 + l];
                uint2 u2 = S1f8[S_OF(e2) * 16 + l];
                uint2 u3 = S1f8[S_OF(e3) * 16 + l];
                FMA_FP8(u0, W_OF(e0))
                FMA_FP8(u1, W_OF(e1))
                FMA_FP8(u2, W_OF(e2))
                FMA_FP8(u3, W_OF(e3))
            }
            for (; t < cnt; t++) {
                long long eb = __shfl(epk, t, 16);
                uint2 u = S1f8[S_OF(eb) * 16 + l];
                FMA_FP8(u, W_OF(eb))
            }
        }
    }
    float* rr = &red[qw][l * 8];
    rr[0] = a0; rr[1] = a1; rr[2] = a2; rr[3] = a3;
    rr[4] = a4; rr[5] = a5; rr[6] = a6; rr[7] = a7;
    __syncthreads();
    int d = threadIdx.x;
    if (d < 128) {
        float s = 0.f;
#pragma unroll
        for (int q = 0; q < 16; q++) s += red[q][d];
        gpart[(size_t)(g * SPLIT + p) * 128 + d] = s;
    }
}

// ======================= graph bounds + FF ==================================

__global__ __launch_bounds__(256)
void bounds_kernel(const int* __restrict__ gid, int* __restrict__ ptr, int n) {
    int i = blockIdx.x * 256 + threadIdx.x;
    if (i >= n) return;
    int b = gid[i];
    int a = (i == 0) ? -1 : gid[i - 1];
    for (int g = a + 1; g <= b; g++) ptr[g] = i;
    if (i == n - 1) {
        for (int g = b + 1; g <= G; g++) ptr[g] = n;
    }
}

// pooled[g] = (sum_p gpart) @ W2 / cnt + b2, then 3-layer FF + shortcut + sigmoid
__global__ __launch_bounds__(128)
void ff_kernel(const float* __restrict__ gpart, const int* __restrict__ gptr,
               const float* __restrict__ W2, const float* __restrict__ b2,
               const float* __restrict__ W1, const float* __restrict__ b1,
               const float* __restrict__ Wf2, const float* __restrict__ bf2,
               const float* __restrict__ W3, const float* __restrict__ b3,
               const float* __restrict__ Wsc, const float* __restrict__ bsc,
               float* __restrict__ ffout) {
    __shared__ float gs[D], hx[D], za[D], zb[D];
    int g = blockIdx.x, d = threadIdx.x;
    float s = 0.f;
#pragma unroll
    for (int p = 0; p < SPLIT; p++)
        s += gpart[(size_t)(g * SPLIT + p) * 128 + d];
    gs[d] = s;
    __syncthreads();
    int cnt = gptr[g + 1] - gptr[g];
    s = 0.f;
    for (int k = 0; k < D; k++) s = fmaf(gs[k], W2[k * D + d], s);
    hx[d] = (cnt > 0) ? (s / (float)cnt + b2[d]) : 0.f;
    __syncthreads();
    s = b1[d];
    for (int k = 0; k < D; k++) s = fmaf(hx[k], W1[k * D + d], s);
    za[d] = fmaxf(s, 0.f);
    __syncthreads();
    s = bf2[d];
    for (int k = 0; k < D; k++) s = fmaf(za[k], Wf2[k * D + d], s);
    zb[d] = fmaxf(s, 0.f);
    __syncthreads();
    s = b3[d];
    for (int k = 0; k < D; k++) s = fmaf(zb[k], W3[k * D + d], s);
    float z3 = fmaxf(s, 0.f);
    float sc = bsc[d];
    for (int k = 0; k < D; k++) sc = fmaf(hx[k], Wsc[k * D + d], sc);
    float v = z3 + sc;
    ffout[g * D + d] = 1.f / (1.f + expf(-v));
}

__global__ __launch_bounds__(256)
void scatter_kernel(const float* __restrict__ ffout, const int* __restrict__ gid,
                    float* __restrict__ out, int n) {
    unsigned idx = blockIdx.x * 256u + threadIdx.x;
    unsigned node = idx >> 5;
    if (node >= (unsigned)n) return;
    int d0 = (idx & 31) * 4;
    int g = gid[node];
    *(float4*)(out + (size_t)node * D + d0) = *(const float4*)(ffout + g * D + d0);
}

extern "C" void kernel_launch(void* const* d_in, const int* in_sizes, int n_in,
                              void* d_out, int out_size, void* d_ws, size_t ws_size,
                              hipStream_t stream) {
    const float* feat = (const float*)d_in[0];
    const float* ew   = (const float*)d_in[1];
    const float* W1   = (const float*)d_in[2];
    const float* b1   = (const float*)d_in[3];
    const float* W2   = (const float*)d_in[4];
    const float* b2   = (const float*)d_in[5];
    const float* ffW1 = (const float*)d_in[6];
    const float* ffb1 = (const float*)d_in[7];
    const float* ffW2 = (const float*)d_in[8];
    const float* ffb2 = (const float*)d_in[9];
    const float* ffW3 = (const float*)d_in[10];
    const float* ffb3 = (const float*)d_in[11];
    const float* ffWs = (const float*)d_in[12];
    const float* ffbs = (const float*)d_in[13];
    const int* esrc = (const int*)d_in[14];
    const int* edst = (const int*)d_in[15];
    const int* gid  = (const int*)d_in[16];

    const int N = in_sizes[0] / D;
    const int E = in_sizes[1];
    float* out = (float*)d_out;

    const int rpb = (N + NB - 1) / NB;        // 196 (<=256 required by bucket_sort)
    const int chunk = (E + NBLK - 1) / NBLK;  // edges per scatter block

    // workspace layout
    char* ws = (char*)d_ws;
    int2* ep = (int2*)ws;                                   // E int2 = 12.8MB
    unsigned char* A = (unsigned char*)(ep + E);            // N*128 fp8 = 12.8MB
    int2* tmp_p = (int2*)(A + (size_t)N * D);               // E int2 = 12.8MB (packed)
    float* ffo = (float*)(tmp_p + E);                       // G*D
    int* gptr = (int*)(ffo + G * D);                        // G+1 (+pad)
    int* row_ptr = gptr + G + 2;                            // N+1
    int* bbase = row_ptr + N + 1;                           // NB+1
    int* bsum = bbase + NB + 1;                             // NB
    int* counts = bsum + NB;                                // NB*NBLK = 1MB
    short* WT1 = (short*)(counts + NB * NBLK);              // 128*128 bf16
    float* gpart = (float*)(WT1 + 128 * 128);               // G*SPLIT*128 = 1MB

    unsigned char* S1 = (unsigned char*)d_out;  // fp8 layer-1 act (front 12.8MB)

    const dim3 blk(256);
    const dim3 blk1k(1024);
    const int nGrid = (N + 255) / 256;
    const int ngroups = (N + 15) / 16;
    const int gemmGrid = (ngroups + 7) / 8;

    // ---- weight transpose+bf16 (tiny)
    prep_wt<<<64, blk, 0, stream>>>(W1, WT1);

    // ---- CSR build (atomic-free radix partition; LDS atomics only)
    radix_count<<<NBLK, blk1k, 0, stream>>>(edst, counts, E, rpb, chunk);
    radix_scan_rel<<<NB, blk, 0, stream>>>(counts, bsum);
    radix_base<<<1, NB, 0, stream>>>(bsum, bbase, row_ptr, E, N);
    radix_scatter<<<NBLK, blk1k, 0, stream>>>(esrc, edst, ew, counts, bbase,
                                              tmp_p, E, rpb, chunk);
    bucket_sort<<<NB, blk, 0, stream>>>(tmp_p, bbase, ep, row_ptr, N, rpb);

    // ---- graph boundaries from sorted gid
    bounds_kernel<<<nGrid, blk, 0, stream>>>(gid, gptr, N);

    // ---- pipeline
    // A1 = fp8(feat @ W1)
    gemm_mfma_f32in<<<gemmGrid, blk, 0, stream>>>(feat, WT1, A, N);
    // S1 = fp8(relu(spmm(A1) + b1))
    spmm_csr_fused<<<(N + 15) / 16, blk, 0, stream>>>((const uint2*)A, (const long long*)ep,
                                                      row_ptr, b1, (uint2*)S1, N);
    // gpart = per-graph partial sums of w_e * S1[src_e]
    graph_sum<<<G * SPLIT, blk, 0, stream>>>((const uint2*)S1, (const long long*)ep,
                                             row_ptr, gptr, gpart);
    // pooled = (sum gpart) @ W2 / cnt + b2; FF MLP + shortcut + sigmoid
    ff_kernel<<<G, 128, 0, stream>>>(gpart, gptr, W2, b2,
                                     ffW1, ffb1, ffW2, ffb2,
                                     ffW3, ffb3, ffWs, ffbs, ffo);
    // out[n] = ffo[graph_id[n]]
    scatter_kernel<<<(int)(((size_t)N * 32 + 255) / 256), blk, 0, stream>>>(ffo, gid, out, N);
}

// Round 17
// 181.712 us; speedup vs baseline: 1.8770x; 1.0010x over previous
//
#include <hip/hip_runtime.h>
#include <math.h>

// ---------------------------------------------------------------------------
// Encoder: GCN(2 layers) + per-graph mean pool + FF MLP on pooled rows + sigmoid
// N=100000 nodes, E=1600000 edges, D=128, G=256 graphs (graph_id sorted)
// Round 17: packed-f32 FMA in the gather loops.
//   r16 counters: spmm VALUBusy 41% = 17.8us of VALU; 8 scalar v_fmac per
//   edge-lane (compiler doesn't pack). Keep accumulators as 4x f32x2 and use
//   vector arithmetic so LLVM emits v_pk_fma_f32 (2 FMA/instr):
//   15 -> ~11 VALU ops per edge-lane in spmm_csr_fused AND graph_sum.
// ---------------------------------------------------------------------------

#define D 128
#define G 256
#define NB 512     // dst buckets (rows-per-bucket = ceil(N/NB) = 196 <= 256)
#define NBLK 512   // scatter blocks (each owns a contiguous edge chunk)
#define SPLIT 8    // partial-sum blocks per graph in graph_sum (deterministic)

typedef __attribute__((ext_vector_type(8))) short bf16x8;
typedef __attribute__((ext_vector_type(4))) float f32x4;
typedef __attribute__((ext_vector_type(2))) float f32x2;

__device__ __forceinline__ unsigned short f2bf(float f) {
    unsigned u = __float_as_uint(f);
    unsigned r = (u + 0x7fffu + ((u >> 16) & 1u)) >> 16;   // round-nearest-even
    return (unsigned short)r;
}

// pack 4 f32 -> 4 fp8 e4m3 bytes (byte i = value i)
__device__ __forceinline__ unsigned pack_fp8x4(float a, float b, float c, float d) {
    int v = __builtin_amdgcn_cvt_pk_fp8_f32(a, b, 0, false);   // bytes 0,1
    v = __builtin_amdgcn_cvt_pk_fp8_f32(c, d, v, true);        // bytes 2,3
    return (unsigned)v;
}

// fma 8 fp8 dims (one uint2) into 4 packed f32x2 accumulators (v_pk_fma_f32)
#define FMA_FP8(u, w)                                                   \
    {                                                                   \
        f32x2 wv = {(w), (w)};                                          \
        f32x2 q0 = __builtin_amdgcn_cvt_pk_f32_fp8((int)(u).x, false);  \
        f32x2 q1 = __builtin_amdgcn_cvt_pk_f32_fp8((int)(u).x, true);   \
        f32x2 q2 = __builtin_amdgcn_cvt_pk_f32_fp8((int)(u).y, false);  \
        f32x2 q3 = __builtin_amdgcn_cvt_pk_f32_fp8((int)(u).y, true);   \
        a01 += wv * q0;                                                 \
        a23 += wv * q1;                                                 \
        a45 += wv * q2;                                                 \
        a67 += wv * q3;                                                 \
    }

#define W_OF(e) __uint_as_float((unsigned)((unsigned long long)(e) >> 32))
#define S_OF(e) ((size_t)(int)(e))

// 8 independent gathers issued back-to-back, then 8 packed-FMA groups
#define GF8(TBL, epk, B)                                                \
    {                                                                   \
        long long x0 = __shfl((epk), (B) + 0, 16);                      \
        long long x1 = __shfl((epk), (B) + 1, 16);                      \
        long long x2 = __shfl((epk), (B) + 2, 16);                      \
        long long x3 = __shfl((epk), (B) + 3, 16);                      \
        long long x4 = __shfl((epk), (B) + 4, 16);                      \
        long long x5 = __shfl((epk), (B) + 5, 16);                      \
        long long x6 = __shfl((epk), (B) + 6, 16);                      \
        long long x7 = __shfl((epk), (B) + 7, 16);                      \
        uint2 v0 = (TBL)[S_OF(x0) * 16 + l];                            \
        uint2 v1 = (TBL)[S_OF(x1) * 16 + l];                            \
        uint2 v2 = (TBL)[S_OF(x2) * 16 + l];                            \
        uint2 v3 = (TBL)[S_OF(x3) * 16 + l];                            \
        uint2 v4 = (TBL)[S_OF(x4) * 16 + l];                            \
        uint2 v5 = (TBL)[S_OF(x5) * 16 + l];                            \
        uint2 v6 = (TBL)[S_OF(x6) * 16 + l];                            \
        uint2 v7 = (TBL)[S_OF(x7) * 16 + l];                            \
        FMA_FP8(v0, W_OF(x0))                                           \
        FMA_FP8(v1, W_OF(x1))                                           \
        FMA_FP8(v2, W_OF(x2))                                           \
        FMA_FP8(v3, W_OF(x3))                                           \
        FMA_FP8(v4, W_OF(x4))                                           \
        FMA_FP8(v5, W_OF(x5))                                           \
        FMA_FP8(v6, W_OF(x6))                                           \
        FMA_FP8(v7, W_OF(x7))                                           \
    }

// ---- one-time: WT1[c][k] = bf16(W1[k][c])  (128x128)
__global__ __launch_bounds__(256)
void prep_wt(const float* __restrict__ W, short* __restrict__ WT) {
    int idx = blockIdx.x * 256 + threadIdx.x;
    if (idx >= 128 * 128) return;
    int k = idx >> 7, c = idx & 127;
    WT[c * 128 + k] = (short)f2bf(W[k * 128 + c]);
}

// ---- MFMA GEMM (fp32 input): Y_fp8 = X_f32 @ W   (WT = W^T bf16)
__global__ __launch_bounds__(256, 2)
void gemm_mfma_f32in(const float* __restrict__ X, const short* __restrict__ WT,
                     unsigned char* __restrict__ Y, int nrows) {
    const int lane = threadIdx.x & 63;
    const int lr = lane & 15;
    const int lq = lane >> 4;
    const int wid = blockIdx.x * 4 + (threadIdx.x >> 6);
    const int nwaves = gridDim.x * 4;
    const int ngroups = (nrows + 15) >> 4;

    bf16x8 wf[8][4];
#pragma unroll
    for (int mt = 0; mt < 8; mt++)
#pragma unroll
        for (int ks = 0; ks < 4; ks++)
            wf[mt][ks] = *(const bf16x8*)(WT + (mt * 16 + lr) * 128 + ks * 32 + lq * 8);

    for (int g = wid; g < ngroups; g += nwaves) {
        int node = g * 16 + lr;
        int nrow = min(node, nrows - 1);
        const float* xp = X + (size_t)nrow * D + lq * 8;
        f32x4 acc[8];
#pragma unroll
        for (int mt = 0; mt < 8; mt++) acc[mt] = (f32x4){0.f, 0.f, 0.f, 0.f};

#pragma unroll
        for (int ks = 0; ks < 4; ks++) {
            float4 v0 = *(const float4*)(xp + ks * 32);
            float4 v1 = *(const float4*)(xp + ks * 32 + 4);
            bf16x8 xb;
            xb[0] = (short)f2bf(v0.x);
            xb[1] = (short)f2bf(v0.y);
            xb[2] = (short)f2bf(v0.z);
            xb[3] = (short)f2bf(v0.w);
            xb[4] = (short)f2bf(v1.x);
            xb[5] = (short)f2bf(v1.y);
            xb[6] = (short)f2bf(v1.z);
            xb[7] = (short)f2bf(v1.w);
#pragma unroll
            for (int mt = 0; mt < 8; mt++)
                acc[mt] = __builtin_amdgcn_mfma_f32_16x16x32_bf16(wf[mt][ks], xb, acc[mt], 0, 0, 0);
        }

        if (node < nrows) {
            unsigned char* yp = Y + (size_t)node * D + lq * 4;
#pragma unroll
            for (int mt = 0; mt < 8; mt++) {
                unsigned o = pack_fp8x4(acc[mt][0], acc[mt][1], acc[mt][2], acc[mt][3]);
                *(unsigned*)(yp + mt * 16) = o;
            }
        }
    }
}

// ============== CSR build: atomic-free radix partition + bucket sort ========

__global__ __launch_bounds__(1024)
void radix_count(const int* __restrict__ dst, int* __restrict__ counts,
                 int ne, int rpb, int chunk) {
    __shared__ int h[NB];
    for (int i = threadIdx.x; i < NB; i += 1024) h[i] = 0;
    __syncthreads();
    int b = blockIdx.x;
    int lo = b * chunk, hi = min(lo + chunk, ne);
    for (int e = lo + threadIdx.x; e < hi; e += 1024)
        atomicAdd(&h[dst[e] / rpb], 1);
    __syncthreads();
    for (int k = threadIdx.x; k < NB; k += 1024)
        counts[k * NBLK + b] = h[k];
}

__global__ __launch_bounds__(256)
void radix_scan_rel(int* __restrict__ counts, int* __restrict__ bsum) {
    __shared__ int s[256];
    int k = blockIdx.x, t = threadIdx.x;
    int base = k * NBLK + t * 2;
    int v0 = counts[base], v1 = counts[base + 1];
    int sum = v0 + v1;
    s[t] = sum;
    __syncthreads();
    for (int off = 1; off < 256; off <<= 1) {
        int x = (t >= off) ? s[t - off] : 0;
        __syncthreads();
        s[t] += x;
        __syncthreads();
    }
    int ex = s[t] - sum;
    counts[base] = ex;
    counts[base + 1] = ex + v0;
    if (t == 255) bsum[k] = s[255];
}

__global__ __launch_bounds__(NB)
void radix_base(const int* __restrict__ bsum, int* __restrict__ bbase,
                int* __restrict__ row_ptr, int ne, int n) {
    __shared__ int s[NB];
    int t = threadIdx.x;
    int v = bsum[t];
    s[t] = v;
    __syncthreads();
    for (int off = 1; off < NB; off <<= 1) {
        int x = (t >= off) ? s[t - off] : 0;
        __syncthreads();
        s[t] += x;
        __syncthreads();
    }
    bbase[t + 1] = s[t];
    if (t == 0) { bbase[0] = 0; row_ptr[n] = ne; }
}

// ONE 8B record per edge: (src | lr<<20, w_fp32). src<2^20, lr<256.
__global__ __launch_bounds__(1024)
void radix_scatter(const int* __restrict__ src, const int* __restrict__ dst,
                   const float* __restrict__ ew,
                   const int* __restrict__ counts, const int* __restrict__ bbase,
                   int2* __restrict__ tmp_p, int ne, int rpb, int chunk) {
    __shared__ int cur[NB];
    int b = blockIdx.x;
    for (int k = threadIdx.x; k < NB; k += 1024)
        cur[k] = bbase[k] + counts[k * NBLK + b];
    __syncthreads();
    int lo = b * chunk, hi = min(lo + chunk, ne);
    for (int e = lo + threadIdx.x; e < hi; e += 1024) {
        int d = dst[e];
        int k = d / rpb;
        int pos = atomicAdd(&cur[k], 1);          // LDS atomic
        tmp_p[pos] = make_int2(src[e] | ((d - k * rpb) << 20), __float_as_int(ew[e]));
    }
}

__global__ __launch_bounds__(256)
void bucket_sort(const int2* __restrict__ tmp_p,
                 const int* __restrict__ bbase, int2* __restrict__ ep,
                 int* __restrict__ row_ptr, int n, int rpb) {
    __shared__ int cnt[256], scn[256], cur[256];
    int b = blockIdx.x, t = threadIdx.x;
    int e0 = bbase[b], e1 = bbase[b + 1];
    int r0 = b * rpb;
    cnt[t] = 0;
    __syncthreads();
    for (int i = e0 + t; i < e1; i += 256)
        atomicAdd(&cnt[(unsigned)tmp_p[i].x >> 20], 1);
    __syncthreads();
    int v = cnt[t];
    scn[t] = v;
    __syncthreads();
    for (int off = 1; off < 256; off <<= 1) {
        int x = (t >= off) ? scn[t - off] : 0;
        __syncthreads();
        scn[t] += x;
        __syncthreads();
    }
    int ex = scn[t] - v;
    cur[t] = ex;
    int grow = r0 + t;
    if (t < rpb && grow < n) row_ptr[grow] = e0 + ex;
    __syncthreads();
    for (int i = e0 + t; i < e1; i += 256) {
        int2 rec = tmp_p[i];
        int r = (unsigned)rec.x >> 20;
        int pos = e0 + atomicAdd(&cur[r], 1);     // LDS atomic
        ep[pos] = make_int2(rec.x & 0xFFFFF, rec.y);
    }
}

// ---- Layer-1 SpMM: quarter-wave per row (16 lanes x uint2 = 128B fp8 row);
// full tiles = 2x batch-8 gathers, packed-FMA accumulate; relu(.+b1)->fp8 out.
__global__ __launch_bounds__(256)
void spmm_csr_fused(const uint2* __restrict__ Xf8, const long long* __restrict__ ep,
                    const int* __restrict__ rp, const float* __restrict__ bias,
                    uint2* __restrict__ outv, int nrows) {
    int row = blockIdx.x * 16 + (threadIdx.x >> 4);
    if (row >= nrows) return;
    int l = threadIdx.x & 15;             // dim-octet index (8 dims)
    int beg = rp[row], end = rp[row + 1];
    f32x2 a01 = {0.f, 0.f}, a23 = {0.f, 0.f}, a45 = {0.f, 0.f}, a67 = {0.f, 0.f};

    for (int t0 = beg; t0 < end; t0 += 16) {
        int j = t0 + l;
        long long epk = (j < end) ? __builtin_nontemporal_load(ep + j) : 0ll;
        if (end - t0 >= 16) {
            GF8(Xf8, epk, 0)
            GF8(Xf8, epk, 8)
        } else {
            int cnt = end - t0;
            int t = 0;
            for (; t + 4 <= cnt; t += 4) {
                long long e0 = __shfl(epk, t, 16);
                long long e1 = __shfl(epk, t + 1, 16);
                long long e2 = __shfl(epk, t + 2, 16);
                long long e3 = __shfl(epk, t + 3, 16);
                uint2 u0 = Xf8[S_OF(e0) * 16 + l];
                uint2 u1 = Xf8[S_OF(e1) * 16 + l];
                uint2 u2 = Xf8[S_OF(e2) * 16 + l];
                uint2 u3 = Xf8[S_OF(e3) * 16 + l];
                FMA_FP8(u0, W_OF(e0))
                FMA_FP8(u1, W_OF(e1))
                FMA_FP8(u2, W_OF(e2))
                FMA_FP8(u3, W_OF(e3))
            }
            for (; t < cnt; t++) {
                long long eb = __shfl(epk, t, 16);
                uint2 u = Xf8[S_OF(eb) * 16 + l];
                FMA_FP8(u, W_OF(eb))
            }
        }
    }
    const float4 b0 = *(const float4*)(bias + l * 8);
    const float4 b1v = *(const float4*)(bias + l * 8 + 4);
    float r0 = fmaxf(a01[0] + b0.x, 0.f),  r1 = fmaxf(a01[1] + b0.y, 0.f);
    float r2 = fmaxf(a23[0] + b0.z, 0.f),  r3 = fmaxf(a23[1] + b0.w, 0.f);
    float r4 = fmaxf(a45[0] + b1v.x, 0.f), r5 = fmaxf(a45[1] + b1v.y, 0.f);
    float r6 = fmaxf(a67[0] + b1v.z, 0.f), r7 = fmaxf(a67[1] + b1v.w, 0.f);
    uint2 p;
    p.x = pack_fp8x4(r0, r1, r2, r3);
    p.y = pack_fp8x4(r4, r5, r6, r7);
    outv[(size_t)row * 16 + l] = p;   // fp8 row = 128B = 16 uint2
}

// ---- graph_sum: gpart[g*SPLIT+p][d] = Sum_{edge chunk} w_e * S1[src_e][d]
__global__ __launch_bounds__(256)
void graph_sum(const uint2* __restrict__ S1f8, const long long* __restrict__ ep,
               const int* __restrict__ rp, const int* __restrict__ gptr,
               float* __restrict__ gpart) {
    __shared__ float red[16][128];   // 8KB
    int g = blockIdx.x / SPLIT, p = blockIdx.x % SPLIT;
    int e0s = rp[gptr[g]], e1s = rp[gptr[g + 1]];
    int len = e1s - e0s;
    int blo = e0s + (int)((long long)len * p / SPLIT);
    int bhi = e0s + (int)((long long)len * (p + 1) / SPLIT);
    int qw = threadIdx.x >> 4;       // 16 quarter-waves
    int l = threadIdx.x & 15;        // dim-octet (8 dims)
    f32x2 a01 = {0.f, 0.f}, a23 = {0.f, 0.f}, a45 = {0.f, 0.f}, a67 = {0.f, 0.f};

    for (int t0 = blo + qw * 16; t0 < bhi; t0 += 256) {
        int j = t0 + l;
        long long epk = (j < bhi) ? __builtin_nontemporal_load(ep + j) : 0ll;
        if (bhi - t0 >= 16) {
            GF8(S1f8, epk, 0)
            GF8(S1f8, epk, 8)
        } else {
            int cnt = bhi - t0;
            int t = 0;
            for (; t + 4 <= cnt; t += 4) {
                long long e0 = __shfl(epk, t, 16);
                long long e1 = __shfl(epk, t + 1, 16);
                long long e2 = __shfl(epk, t + 2, 16);
                long long e3 = __shfl(epk, t + 3, 16);
                uint2 u0 = S1f8[S_OF(e0) * 16 + l];
                uint2 u1 = S1f8[S_OF(e1) * 16 + l];
                uint2 u2 = S1f8[S_OF(e2) * 16 + l];
                uint2 u3 = S1f8[S_OF(e3) * 16 + l];
                FMA_FP8(u0, W_OF(e0))
                FMA_FP8(u1, W_OF(e1))
                FMA_FP8(u2, W_OF(e2))
                FMA_FP8(u3, W_OF(e3))
            }
            for (; t < cnt; t++) {
                long long eb = __shfl(epk, t, 16);
                uint2 u = S1f8[S_OF(eb) * 16 + l];
                FMA_FP8(u, W_OF(eb))
            }
        }
    }
    float* rr = &red[qw][l * 8];
    rr[0] = a01[0]; rr[1] = a01[1]; rr[2] = a23[0]; rr[3] = a23[1];
    rr[4] = a45[0]; rr[5] = a45[1]; rr[6] = a67[0]; rr[7] = a67[1];
    __syncthreads();
    int d = threadIdx.x;
    if (d < 128) {
        float s = 0.f;
#pragma unroll
        for (int q = 0; q < 16; q++) s += red[q][d];
        gpart[(size_t)(g * SPLIT + p) * 128 + d] = s;
    }
}

// ======================= graph bounds + FF ==================================

__global__ __launch_bounds__(256)
void bounds_kernel(const int* __restrict__ gid, int* __restrict__ ptr, int n) {
    int i = blockIdx.x * 256 + threadIdx.x;
    if (i >= n) return;
    int b = gid[i];
    int a = (i == 0) ? -1 : gid[i - 1];
    for (int g = a + 1; g <= b; g++) ptr[g] = i;
    if (i == n - 1) {
        for (int g = b + 1; g <= G; g++) ptr[g] = n;
    }
}

// pooled[g] = (sum_p gpart) @ W2 / cnt + b2, then 3-layer FF + shortcut + sigmoid
__global__ __launch_bounds__(128)
void ff_kernel(const float* __restrict__ gpart, const int* __restrict__ gptr,
               const float* __restrict__ W2, const float* __restrict__ b2,
               const float* __restrict__ W1, const float* __restrict__ b1,
               const float* __restrict__ Wf2, const float* __restrict__ bf2,
               const float* __restrict__ W3, const float* __restrict__ b3,
               const float* __restrict__ Wsc, const float* __restrict__ bsc,
               float* __restrict__ ffout) {
    __shared__ float gs[D], hx[D], za[D], zb[D];
    int g = blockIdx.x, d = threadIdx.x;
    float s = 0.f;
#pragma unroll
    for (int p = 0; p < SPLIT; p++)
        s += gpart[(size_t)(g * SPLIT + p) * 128 + d];
    gs[d] = s;
    __syncthreads();
    int cnt = gptr[g + 1] - gptr[g];
    s = 0.f;
    for (int k = 0; k < D; k++) s = fmaf(gs[k], W2[k * D + d], s);
    hx[d] = (cnt > 0) ? (s / (float)cnt + b2[d]) : 0.f;
    __syncthreads();
    s = b1[d];
    for (int k = 0; k < D; k++) s = fmaf(hx[k], W1[k * D + d], s);
    za[d] = fmaxf(s, 0.f);
    __syncthreads();
    s = bf2[d];
    for (int k = 0; k < D; k++) s = fmaf(za[k], Wf2[k * D + d], s);
    zb[d] = fmaxf(s, 0.f);
    __syncthreads();
    s = b3[d];
    for (int k = 0; k < D; k++) s = fmaf(zb[k], W3[k * D + d], s);
    float z3 = fmaxf(s, 0.f);
    float sc = bsc[d];
    for (int k = 0; k < D; k++) sc = fmaf(hx[k], Wsc[k * D + d], sc);
    float v = z3 + sc;
    ffout[g * D + d] = 1.f / (1.f + expf(-v));
}

__global__ __launch_bounds__(256)
void scatter_kernel(const float* __restrict__ ffout, const int* __restrict__ gid,
                    float* __restrict__ out, int n) {
    unsigned idx = blockIdx.x * 256u + threadIdx.x;
    unsigned node = idx >> 5;
    if (node >= (unsigned)n) return;
    int d0 = (idx & 31) * 4;
    int g = gid[node];
    *(float4*)(out + (size_t)node * D + d0) = *(const float4*)(ffout + g * D + d0);
}

extern "C" void kernel_launch(void* const* d_in, const int* in_sizes, int n_in,
                              void* d_out, int out_size, void* d_ws, size_t ws_size,
                              hipStream_t stream) {
    const float* feat = (const float*)d_in[0];
    const float* ew   = (const float*)d_in[1];
    const float* W1   = (const float*)d_in[2];
    const float* b1   = (const float*)d_in[3];
    const float* W2   = (const float*)d_in[4];
    const float* b2   = (const float*)d_in[5];
    const float* ffW1 = (const float*)d_in[6];
    const float* ffb1 = (const float*)d_in[7];
    const float* ffW2 = (const float*)d_in[8];
    const float* ffb2 = (const float*)d_in[9];
    const float* ffW3 = (const float*)d_in[10];
    const float* ffb3 = (const float*)d_in[11];
    const float* ffWs = (const float*)d_in[12];
    const float* ffbs = (const float*)d_in[13];
    const int* esrc = (const int*)d_in[14];
    const int* edst = (const int*)d_in[15];
    const int* gid  = (const int*)d_in[16];

    const int N = in_sizes[0] / D;
    const int E = in_sizes[1];
    float* out = (float*)d_out;

    const int rpb = (N + NB - 1) / NB;        // 196 (<=256 required by bucket_sort)
    const int chunk = (E + NBLK - 1) / NBLK;  // edges per scatter block

    // workspace layout
    char* ws = (char*)d_ws;
    int2* ep = (int2*)ws;                                   // E int2 = 12.8MB
    unsigned char* A = (unsigned char*)(ep + E);            // N*128 fp8 = 12.8MB
    int2* tmp_p = (int2*)(A + (size_t)N * D);               // E int2 = 12.8MB (packed)
    float* ffo = (float*)(tmp_p + E);                       // G*D
    int* gptr = (int*)(ffo + G * D);                        // G+1 (+pad)
    int* row_ptr = gptr + G + 2;                            // N+1
    int* bbase = row_ptr + N + 1;                           // NB+1
    int* bsum = bbase + NB + 1;                             // NB
    int* counts = bsum + NB;                                // NB*NBLK = 1MB
    short* WT1 = (short*)(counts + NB * NBLK);              // 128*128 bf16
    float* gpart = (float*)(WT1 + 128 * 128);               // G*SPLIT*128 = 1MB

    unsigned char* S1 = (unsigned char*)d_out;  // fp8 layer-1 act (front 12.8MB)

    const dim3 blk(256);
    const dim3 blk1k(1024);
    const int nGrid = (N + 255) / 256;
    const int ngroups = (N + 15) / 16;
    const int gemmGrid = (ngroups + 7) / 8;

    // ---- weight transpose+bf16 (tiny)
    prep_wt<<<64, blk, 0, stream>>>(W1, WT1);

    // ---- CSR build (atomic-free radix partition; LDS atomics only)
    radix_count<<<NBLK, blk1k, 0, stream>>>(edst, counts, E, rpb, chunk);
    radix_scan_rel<<<NB, blk, 0, stream>>>(counts, bsum);
    radix_base<<<1, NB, 0, stream>>>(bsum, bbase, row_ptr, E, N);
    radix_scatter<<<NBLK, blk1k, 0, stream>>>(esrc, edst, ew, counts, bbase,
                                              tmp_p, E, rpb, chunk);
    bucket_sort<<<NB, blk, 0, stream>>>(tmp_p, bbase, ep, row_ptr, N, rpb);

    // ---- graph boundaries from sorted gid
    bounds_kernel<<<nGrid, blk, 0, stream>>>(gid, gptr, N);

    // ---- pipeline
    // A1 = fp8(feat @ W1)
    gemm_mfma_f32in<<<gemmGrid, blk, 0, stream>>>(feat, WT1, A, N);
    // S1 = fp8(relu(spmm(A1) + b1))
    spmm_csr_fused<<<(N + 15) / 16, blk, 0, stream>>>((const uint2*)A, (const long long*)ep,
                                                      row_ptr, b1, (uint2*)S1, N);
    // gpart = per-graph partial sums of w_e * S1[src_e]
    graph_sum<<<G * SPLIT, blk, 0, stream>>>((const uint2*)S1, (const long long*)ep,
                                             row_ptr, gptr, gpart);
    // pooled = (sum gpart) @ W2 / cnt + b2; FF MLP + shortcut + sigmoid
    ff_kernel<<<G, 128, 0, stream>>>(gpart, gptr, W2, b2,
                                     ffW1, ffb1, ffW2, ffb2,
                                     ffW3, ffb3, ffWs, ffbs, ffo);
    // out[n] = ffo[graph_id[n]]
    scatter_kernel<<<(int)(((size_t)N * 32 + 255) / 256), blk, 0, stream>>>(ffo, gid, out, N);
}